// Round 10
// baseline (407.272 us; speedup 1.0000x reference)
//
#include <hip/hip_runtime.h>
#include <cstddef>

typedef __attribute__((ext_vector_type(8))) short short8;
typedef __attribute__((ext_vector_type(4))) float f32x4;
typedef __attribute__((ext_vector_type(8))) _Float16 half8;
typedef __attribute__((ext_vector_type(2))) _Float16 half2v;

union H8 { half8 v; half2v p[4]; unsigned int w[4]; };
union W1H2 { unsigned int w; half2v p; };

__device__ __forceinline__ unsigned short f2h(float f) {
    union { _Float16 h; unsigned short u; } x; x.h = (_Float16)f; return x.u;
}
__device__ __forceinline__ float h2f(unsigned short u) {
    union { unsigned short u; _Float16 h; } x; x.u = u; return (float)x.h;
}
__device__ __forceinline__ float lrelu(float v) { return v > 0.f ? v : 0.2f * v; }

// async global->LDS, 16 B per lane; LDS dest is wave-uniform base + lane*16.
__device__ __forceinline__ void gl_lds16(const void* g, void* l) {
    __builtin_amdgcn_global_load_lds(
        (const __attribute__((address_space(1))) void*)g,
        (__attribute__((address_space(3))) void*)l, 16, 0, 0);
}

// ---------------- CSR build ----------------

__global__ void count_edges_kernel(const int* __restrict__ ei, int E, int N,
                                   int* __restrict__ cnt) {
    int e = blockIdx.x * blockDim.x + threadIdx.x;
    if (e >= E + N) return;
    int d = (e < E) ? ei[E + e] : (e - E);  // self loops appended
    atomicAdd(&cnt[d], 1);
}

__global__ void scan_p1_kernel(const int* __restrict__ cnt, int* __restrict__ rp,
                               int* __restrict__ bsum, int n) {
    __shared__ int sh[256];
    int t = threadIdx.x, i = blockIdx.x * 256 + t;
    sh[t] = (i < n) ? cnt[i] : 0;
    __syncthreads();
    for (int off = 1; off < 256; off <<= 1) {
        int u = (t >= off) ? sh[t - off] : 0;
        __syncthreads();
        sh[t] += u;
        __syncthreads();
    }
    if (i < n) rp[i + 1] = sh[t];              // block-local inclusive
    if (t == 255) bsum[blockIdx.x] = sh[255];  // block total
}

__global__ void scan_p3_kernel(int* __restrict__ rp, const int* __restrict__ bsum,
                               int* __restrict__ cnt, int n, int nb) {
    __shared__ int sh[256];
    int t = threadIdx.x;
    sh[t] = (t < nb) ? bsum[t] : 0;            // redundant per-block scan of totals
    __syncthreads();
    for (int off = 1; off < 256; off <<= 1) {
        int u = (t >= off) ? sh[t - off] : 0;
        __syncthreads();
        sh[t] += u;
        __syncthreads();
    }
    int off = (blockIdx.x == 0) ? 0 : sh[blockIdx.x - 1];
    int i = blockIdx.x * 256 + t;
    if (i < n) {
        rp[i + 1] += off;
        cnt[i] = 0;                            // scatter cursor re-zero
    }
    if (i == 0) rp[0] = 0;
}

__global__ void scatter_edges_kernel(const int* __restrict__ ei, int E, int N,
                                     const int* __restrict__ rp, int* __restrict__ cur,
                                     int* __restrict__ csrc) {
    int e = blockIdx.x * blockDim.x + threadIdx.x;
    if (e >= E + N) return;
    int s, d;
    if (e < E) { s = ei[e]; d = ei[E + e]; } else { s = e - E; d = s; }
    int pos = rp[d] + atomicAdd(&cur[d], 1);
    csrc[pos] = s;
}

// ---------------- dtype prep (fused: x->f16 pad + all weight transposes) ----

__global__ void prep_kernel(
    const float* __restrict__ x, unsigned short* __restrict__ xb,
    int rows, int cols, int padRows,
    const float* __restrict__ W1, const float* __restrict__ W2,
    const float* __restrict__ Wm, const float* __restrict__ Wl,
    unsigned short* __restrict__ W1t, unsigned short* __restrict__ W2t,
    unsigned short* __restrict__ WmlT, int xBlocks) {
    if ((int)blockIdx.x < xBlocks) {
        int i = blockIdx.x * blockDim.x + threadIdx.x;
        int total = (padRows * cols) >> 2;
        if (i >= total) return;
        int r = (i * 4) / cols;
        ushort4 o;
        if (r < rows) {
            float4 v = *(const float4*)(x + (size_t)i * 4);
            o = make_ushort4(f2h(v.x), f2h(v.y), f2h(v.z), f2h(v.w));
        } else {
            o = make_ushort4(0, 0, 0, 0);
        }
        *(ushort4*)(xb + (size_t)i * 4) = o;
        return;
    }
    int i = (blockIdx.x - xBlocks) * blockDim.x + threadIdx.x;
    if (i < 65536) {
        int k = i >> 8, n = i & 255;
        W1t[(size_t)n * 256 + k] = f2h(W1[i]);
    } else if (i < 65536 + 131072) {
        int j = i - 65536;
        int k = j >> 9, n = j & 511;
        W2t[(size_t)n * 256 + k] = f2h(W2[j]);
    } else if (i < 65536 + 131072 + 65536) {
        int j = i - 196608;
        int k = j >> 7, n = j & 127;
        WmlT[(size_t)n * 512 + k] = f2h(Wm[j]);
    } else if (i < 65536 + 131072 + 131072) {
        int j = i - 262144;
        int k = j >> 7, n = j & 127;
        WmlT[(size_t)(128 + n) * 512 + k] = f2h(Wl[j]);
    }
}

// ---------------- f16 MFMA GEMM (global_load_lds staging) + al epilogue ----

__global__ __launch_bounds__(256) void gemm_f16_kernel(
    const unsigned short* __restrict__ A, const unsigned short* __restrict__ Bt,
    unsigned short* __restrict__ C, int M, int K, int Nc,
    float* __restrict__ al_s, float* __restrict__ al_d,
    const float* __restrict__ aslo, const float* __restrict__ adlo,
    const float* __restrict__ ashi, const float* __restrict__ adhi,
    int csplit, int Chead, int H) {
    __shared__ short As[64 * 32];
    __shared__ short Bs[128 * 32];
    __shared__ float salS[64][4];
    __shared__ float salD[64][4];
    int tid = threadIdx.x;
    int bm = blockIdx.y * 64;
    int bn = blockIdx.x * 128;
    int wave = tid >> 6, lane = tid & 63;
    int wm = (wave >> 1) * 32, wn = (wave & 1) * 64;
    int lm = lane & 15, lq = lane >> 4;

    f32x4 acc[2][4] = {};

    int c0 = tid, c1 = tid + 256;
    const unsigned short* Ap0 = A + (size_t)(bm + (c0 >> 2)) * K + (c0 & 3) * 8;
    const unsigned short* Bp0 = Bt + (size_t)(bn + (c0 >> 2)) * K + (c0 & 3) * 8;
    const unsigned short* Bp1 = Bt + (size_t)(bn + (c1 >> 2)) * K + (c1 & 3) * 8;

    for (int kk = 0; kk < K; kk += 32) {
        __syncthreads();           // prev iter's LDS frag reads done
        gl_lds16(Ap0 + kk, &As[c0 * 8]);
        gl_lds16(Bp0 + kk, &Bs[c0 * 8]);
        gl_lds16(Bp1 + kk, &Bs[c1 * 8]);
        __syncthreads();           // vmcnt drain + tile resident
        half8 af[2], bf[4];
#pragma unroll
        for (int t = 0; t < 2; t++)
            af[t] = *(const half8*)&As[(wm + t * 16 + lm) * 32 + lq * 8];
#pragma unroll
        for (int t = 0; t < 4; t++)
            bf[t] = *(const half8*)&Bs[(wn + t * 16 + lm) * 32 + lq * 8];
#pragma unroll
        for (int tm = 0; tm < 2; tm++)
#pragma unroll
            for (int tn = 0; tn < 4; tn++)
                acc[tm][tn] = __builtin_amdgcn_mfma_f32_16x16x32_f16(
                    af[tm], bf[tn], acc[tm][tn], 0, 0, 0);
    }

    // C store (f16)
#pragma unroll
    for (int tm = 0; tm < 2; tm++) {
#pragma unroll
        for (int r = 0; r < 4; r++) {
            int row = bm + wm + tm * 16 + lq * 4 + r;
            if (row < M) {
#pragma unroll
                for (int tn = 0; tn < 4; tn++) {
                    int col = bn + wn + tn * 16 + lm;
                    C[(size_t)row * Nc + col] = f2h(acc[tm][tn][r]);
                }
            }
        }
    }

    // attention-logit partial dots
    float asv[4], adv[4];
#pragma unroll
    for (int tn = 0; tn < 4; tn++) {
        int col = bn + wn + tn * 16 + lm;
        bool hi = col >= csplit;
        int cc = hi ? col - csplit : col;
        asv[tn] = hi ? ashi[cc] : aslo[cc];
        adv[tn] = hi ? adhi[cc] : adlo[cc];
    }
    int gb = wn >> 5;  // 0 or 2
#pragma unroll
    for (int tm = 0; tm < 2; tm++) {
#pragma unroll
        for (int r = 0; r < 4; r++) {
#pragma unroll
            for (int p = 0; p < 2; p++) {
                float s1 = acc[tm][2 * p][r] * asv[2 * p]
                         + acc[tm][2 * p + 1][r] * asv[2 * p + 1];
                float s2 = acc[tm][2 * p][r] * adv[2 * p]
                         + acc[tm][2 * p + 1][r] * adv[2 * p + 1];
#pragma unroll
                for (int off = 8; off >= 1; off >>= 1) {
                    s1 += __shfl_xor(s1, off);
                    s2 += __shfl_xor(s2, off);
                }
                if (lm == 0) {
                    int rl = wm + tm * 16 + lq * 4 + r;
                    salS[rl][gb + p] = s1;
                    salD[rl][gb + p] = s2;
                }
            }
        }
    }
    __syncthreads();
    if (tid < 64) {
        int row = bm + tid;
        if (row < M) {
            int hb = bn / Chead;       // first head in this col-block
            int HB = 128 / Chead;      // heads per col-block (1, 2, or 4)
            int GH = Chead >> 5;       // 32-col groups per head
            for (int i = 0; i < HB; i++) {
                float ss = 0.f, sd = 0.f;
                for (int j = 0; j < GH; j++) {
                    ss += salS[tid][i * GH + j];
                    sd += salD[tid][i * GH + j];
                }
                al_s[(size_t)row * H + hb + i] = ss;
                al_d[(size_t)row * H + hb + i] = sd;
            }
        }
    }
}

// ---------------- per-node softmax -> alphaT[H][Ep] (f16) ----------------

template <int H4>
__global__ __launch_bounds__(256) void alpha_kernel(
    const int* __restrict__ rp, const int* __restrict__ csrc,
    const float* __restrict__ al_s, const float* __restrict__ al_d,
    unsigned short* __restrict__ alphaT, int Ep, int N) {
    const int H = 4 * H4;
    int wv = threadIdx.x >> 6;
    int lane = threadIdx.x & 63;
    int n = blockIdx.x * 4 + wv;
    if (n >= N) return;
    int beg = rp[n], end = rp[n + 1];
    int deg = end - beg;

    float ad[H];
#pragma unroll
    for (int g = 0; g < H4; g++)
        *(float4*)&ad[g * 4] = *(const float4*)(al_d + (size_t)n * H + g * 4);

    if (deg <= 64) {
        bool act = lane < deg;
        int s = act ? csrc[beg + lane] : 0;
        float v[H], m[H], ex[H], sum[H];
#pragma unroll
        for (int g = 0; g < H4; g++) {
            float4 as = *(const float4*)(al_s + (size_t)s * H + g * 4);
            v[g * 4 + 0] = lrelu(as.x + ad[g * 4 + 0]);
            v[g * 4 + 1] = lrelu(as.y + ad[g * 4 + 1]);
            v[g * 4 + 2] = lrelu(as.z + ad[g * 4 + 2]);
            v[g * 4 + 3] = lrelu(as.w + ad[g * 4 + 3]);
        }
#pragma unroll
        for (int j = 0; j < H; j++) m[j] = act ? v[j] : -3.402823466e38f;
#pragma unroll
        for (int off = 32; off >= 1; off >>= 1)
#pragma unroll
            for (int j = 0; j < H; j++) m[j] = fmaxf(m[j], __shfl_xor(m[j], off));
#pragma unroll
        for (int j = 0; j < H; j++) {
            ex[j] = act ? __expf(v[j] - m[j]) : 0.f;
            sum[j] = ex[j];
        }
#pragma unroll
        for (int off = 32; off >= 1; off >>= 1)
#pragma unroll
            for (int j = 0; j < H; j++) sum[j] += __shfl_xor(sum[j], off);
        if (act) {
#pragma unroll
            for (int j = 0; j < H; j++)
                alphaT[(size_t)j * Ep + beg + lane] = f2h(ex[j] / (sum[j] + 1e-16f));
        }
    } else {
        // general path (deg > 64): strided stats with recompute
        float m[H], sum[H];
#pragma unroll
        for (int j = 0; j < H; j++) m[j] = -3.402823466e38f;
        for (int e = beg + lane; e < end; e += 64) {
            int s = csrc[e];
#pragma unroll
            for (int g = 0; g < H4; g++) {
                float4 as = *(const float4*)(al_s + (size_t)s * H + g * 4);
                m[g * 4 + 0] = fmaxf(m[g * 4 + 0], lrelu(as.x + ad[g * 4 + 0]));
                m[g * 4 + 1] = fmaxf(m[g * 4 + 1], lrelu(as.y + ad[g * 4 + 1]));
                m[g * 4 + 2] = fmaxf(m[g * 4 + 2], lrelu(as.z + ad[g * 4 + 2]));
                m[g * 4 + 3] = fmaxf(m[g * 4 + 3], lrelu(as.w + ad[g * 4 + 3]));
            }
        }
#pragma unroll
        for (int off = 32; off >= 1; off >>= 1)
#pragma unroll
            for (int j = 0; j < H; j++) m[j] = fmaxf(m[j], __shfl_xor(m[j], off));
#pragma unroll
        for (int j = 0; j < H; j++) sum[j] = 0.f;
        for (int e = beg + lane; e < end; e += 64) {
            int s = csrc[e];
#pragma unroll
            for (int g = 0; g < H4; g++) {
                float4 as = *(const float4*)(al_s + (size_t)s * H + g * 4);
                sum[g * 4 + 0] += __expf(lrelu(as.x + ad[g * 4 + 0]) - m[g * 4 + 0]);
                sum[g * 4 + 1] += __expf(lrelu(as.y + ad[g * 4 + 1]) - m[g * 4 + 1]);
                sum[g * 4 + 2] += __expf(lrelu(as.z + ad[g * 4 + 2]) - m[g * 4 + 2]);
                sum[g * 4 + 3] += __expf(lrelu(as.w + ad[g * 4 + 3]) - m[g * 4 + 3]);
            }
        }
#pragma unroll
        for (int off = 32; off >= 1; off >>= 1)
#pragma unroll
            for (int j = 0; j < H; j++) sum[j] += __shfl_xor(sum[j], off);
        float r[H];
#pragma unroll
        for (int j = 0; j < H; j++) r[j] = 1.0f / (sum[j] + 1e-16f);
        for (int e = beg + lane; e < end; e += 64) {
            int s = csrc[e];
#pragma unroll
            for (int g = 0; g < H4; g++) {
                float4 as = *(const float4*)(al_s + (size_t)s * H + g * 4);
                alphaT[(size_t)(g * 4 + 0) * Ep + e] =
                    f2h(__expf(lrelu(as.x + ad[g * 4 + 0]) - m[g * 4 + 0]) * r[g * 4 + 0]);
                alphaT[(size_t)(g * 4 + 1) * Ep + e] =
                    f2h(__expf(lrelu(as.y + ad[g * 4 + 1]) - m[g * 4 + 1]) * r[g * 4 + 1]);
                alphaT[(size_t)(g * 4 + 2) * Ep + e] =
                    f2h(__expf(lrelu(as.z + ad[g * 4 + 2]) - m[g * 4 + 2]) * r[g * 4 + 2]);
                alphaT[(size_t)(g * 4 + 3) * Ep + e] =
                    f2h(__expf(lrelu(as.w + ad[g * 4 + 3]) - m[g * 4 + 3]) * r[g * 4 + 3]);
            }
        }
    }
}

// ---- staged channel-sliced aggregation (layers 1 & 2) ----
// NG=64 nodes x one 64-ch slice per block (slice = blockIdx % NS, XCD-pinned).
// Edge span staged as uint2{pre-scaled byte offset, replicated-half2 alpha}.
// NEW: dynamic node queue (LDS atomic) -> 8-lane groups pop nodes on demand,
// so a wave's lifetime tracks the MEAN degree of its popped nodes instead of
// the MAX over fixed assignments (deg~Poisson(17): max-of-8 ~26 vs mean 17).
// That keeps all 8 groups of every wave issuing gathers -> higher MLP.

template <int NS, int HC, int C>
__global__ __launch_bounds__(256) void agg_stage_kernel(
    const int* __restrict__ rp, const int* __restrict__ csrc,
    const unsigned short* __restrict__ alphaT, int Ep,
    const unsigned short* __restrict__ h, const float* __restrict__ bias,
    unsigned short* __restrict__ out, int N) {
    constexpr int NG = 64;
    constexpr int MAXE = 2048;
    __shared__ int lds_rp[NG + 1];
    __shared__ uint2 lds_ea[MAXE];            // {byte offset, packed alpha}
    __shared__ int lds_q;
    int tid = threadIdx.x;
    int bs = blockIdx.x % NS;                 // channel slice (XCD-pinned)
    int g0 = (blockIdx.x / NS) * NG;          // first node of this block
    const int hd = (bs * 64) / C;             // head owning this slice
    if (tid <= NG) {
        int nn = g0 + tid;
        lds_rp[tid] = rp[nn <= N ? nn : N];
    }
    if (tid == 0) lds_q = 0;
    __syncthreads();
    int e0 = lds_rp[0], span = lds_rp[NG] - e0;
    const unsigned short* at = alphaT + (size_t)hd * Ep + e0;
    bool fits = span <= MAXE;
    if (fits) {
        for (int i = tid; i < span; i += 256) {   // coalesced staging
            unsigned int off = (unsigned int)csrc[e0 + i] * (unsigned int)(HC * 2);
            unsigned int a = at[i];
            lds_ea[i] = make_uint2(off, a | (a << 16));
        }
    }
    __syncthreads();

    int lg = tid & 7;                         // 8 ch-lanes per group
    int ch = bs * 64 + lg * 8;
    const unsigned int lo = (unsigned int)ch * 2;   // lane-constant byte base
    const char* hb = (const char*)h;
    const unsigned short* atg = alphaT + (size_t)hd * Ep;

    for (;;) {
        int ln;
        if (lg == 0) ln = atomicAdd(&lds_q, 1);
        ln = __shfl(ln, (threadIdx.x & 63) & 56);   // broadcast from group leader
        if (ln >= NG) break;
        int n = g0 + ln;
        if (n >= N) break;                    // nodes monotone in ln
        H8 A; A.v = half8{};

        if (fits) {
            int t = lds_rp[ln] - e0, end = lds_rp[ln + 1] - e0;
            for (; t + 3 < end; t += 4) {     // 4 loads in flight per group
                uint2 ea0 = lds_ea[t],     ea1 = lds_ea[t + 1];
                uint2 ea2 = lds_ea[t + 2], ea3 = lds_ea[t + 3];
                H8 h0, h1, h2, h3;
                h0.v = *(const half8*)(hb + (ea0.x + lo));
                h1.v = *(const half8*)(hb + (ea1.x + lo));
                h2.v = *(const half8*)(hb + (ea2.x + lo));
                h3.v = *(const half8*)(hb + (ea3.x + lo));
                W1H2 a0, a1, a2, a3;
                a0.w = ea0.y; a1.w = ea1.y; a2.w = ea2.y; a3.w = ea3.y;
#pragma unroll
                for (int i = 0; i < 4; i++) A.p[i] += h0.p[i] * a0.p;
#pragma unroll
                for (int i = 0; i < 4; i++) A.p[i] += h1.p[i] * a1.p;
#pragma unroll
                for (int i = 0; i < 4; i++) A.p[i] += h2.p[i] * a2.p;
#pragma unroll
                for (int i = 0; i < 4; i++) A.p[i] += h3.p[i] * a3.p;
            }
            for (; t < end; t++) {
                uint2 ea0 = lds_ea[t];
                W1H2 a0; a0.w = ea0.y;
                H8 h0; h0.v = *(const half8*)(hb + (ea0.x + lo));
#pragma unroll
                for (int i = 0; i < 4; i++) A.p[i] += h0.p[i] * a0.p;
            }
        } else {                              // pathological span: direct
            for (int t = lds_rp[ln]; t < lds_rp[ln + 1]; t++) {
                unsigned int off = (unsigned int)csrc[t] * (unsigned int)(HC * 2);
                unsigned int a = atg[t];
                W1H2 a0; a0.w = a | (a << 16);
                H8 h0; h0.v = *(const half8*)(hb + (off + lo));
#pragma unroll
                for (int i = 0; i < 4; i++) A.p[i] += h0.p[i] * a0.p;
            }
        }

        short8 o;
#pragma unroll
        for (int i = 0; i < 8; i++)
            o[i] = (short)f2h(fmaxf((float)A.v[i] + bias[ch + i], 0.f));
        *(short8*)(out + (size_t)n * HC + ch) = o;
    }
}

// Layers 3+4 staged: HC=256 = 8 heads x 32 ch; slice o in {0,1} covers one
// output (4 heads, 128 ch). NG=32 nodes/block; 16-lane groups pop nodes from
// the same dynamic queue; head-mean = 2 f32 shuffle rounds at the end.

__global__ __launch_bounds__(256) void agg_mean_stage_kernel(
    const int* __restrict__ rp, const int* __restrict__ csrc,
    const unsigned short* __restrict__ alphaT, int Ep,
    const unsigned short* __restrict__ h,
    const float* __restrict__ bias1, const float* __restrict__ bias2,
    float* __restrict__ out1, float* __restrict__ out2, int N) {
    constexpr int NG = 32;
    constexpr int MAXE = 1024;
    __shared__ int lds_rp[NG + 1];
    __shared__ unsigned int lds_off[MAXE];
    __shared__ unsigned int lds_aw[4][MAXE];
    __shared__ int lds_q;
    int tid = threadIdx.x;
    int o = blockIdx.x & 1;                   // output slice (XCD-spread)
    int g0 = (blockIdx.x >> 1) * NG;
    if (tid <= NG) {
        int nn = g0 + tid;
        lds_rp[tid] = rp[nn <= N ? nn : N];
    }
    if (tid == 0) lds_q = 0;
    __syncthreads();
    int e0 = lds_rp[0], span = lds_rp[NG] - e0;
    bool fits = span <= MAXE;
    if (fits) {
        for (int i = tid; i < span; i += 256)
            lds_off[i] = (unsigned int)csrc[e0 + i] * 512u;  // 256 ch * 2 B
#pragma unroll
        for (int hh = 0; hh < 4; hh++) {
            const unsigned short* at = alphaT + (size_t)(o * 4 + hh) * Ep + e0;
            for (int i = tid; i < span; i += 256) {
                unsigned int a = at[i];
                lds_aw[hh][i] = a | (a << 16);
            }
        }
    }
    __syncthreads();

    int cg = tid & 15;                        // 16 ch-lanes per group
    int hh = cg >> 2;                         // head within slice
    int ch = o * 128 + cg * 8;
    const unsigned int lo = (unsigned int)ch * 2;
    const char* hb = (const char*)h;
    const unsigned short* atg = alphaT + (size_t)(o * 4 + hh) * Ep;

    for (;;) {
        int ln;
        if (cg == 0) ln = atomicAdd(&lds_q, 1);
        ln = __shfl(ln, (threadIdx.x & 63) & 48);   // broadcast from group leader
        if (ln >= NG) break;
        int n = g0 + ln;
        if (n >= N) break;
        H8 A; A.v = half8{};

        if (fits) {
            int t = lds_rp[ln] - e0, end = lds_rp[ln + 1] - e0;
            for (; t + 3 < end; t += 4) {     // 4 loads in flight per group
                unsigned int o0 = lds_off[t],     o1 = lds_off[t + 1];
                unsigned int o2 = lds_off[t + 2], o3 = lds_off[t + 3];
                H8 h0, h1, h2, h3;
                h0.v = *(const half8*)(hb + (o0 + lo));
                h1.v = *(const half8*)(hb + (o1 + lo));
                h2.v = *(const half8*)(hb + (o2 + lo));
                h3.v = *(const half8*)(hb + (o3 + lo));
                W1H2 a0, a1, a2, a3;
                a0.w = lds_aw[hh][t];     a1.w = lds_aw[hh][t + 1];
                a2.w = lds_aw[hh][t + 2]; a3.w = lds_aw[hh][t + 3];
#pragma unroll
                for (int i = 0; i < 4; i++) A.p[i] += h0.p[i] * a0.p;
#pragma unroll
                for (int i = 0; i < 4; i++) A.p[i] += h1.p[i] * a1.p;
#pragma unroll
                for (int i = 0; i < 4; i++) A.p[i] += h2.p[i] * a2.p;
#pragma unroll
                for (int i = 0; i < 4; i++) A.p[i] += h3.p[i] * a3.p;
            }
            for (; t < end; t++) {
                W1H2 a0; a0.w = lds_aw[hh][t];
                H8 h0; h0.v = *(const half8*)(hb + (lds_off[t] + lo));
#pragma unroll
                for (int i = 0; i < 4; i++) A.p[i] += h0.p[i] * a0.p;
            }
        } else {
            for (int t = lds_rp[ln]; t < lds_rp[ln + 1]; t++) {
                unsigned int off = (unsigned int)csrc[t] * 512u;
                unsigned int a = atg[t];
                W1H2 a0; a0.w = a | (a << 16);
                H8 h0; h0.v = *(const half8*)(hb + (off + lo));
#pragma unroll
                for (int i = 0; i < 4; i++) A.p[i] += h0.p[i] * a0.p;
            }
        }

        // head-mean: sum over lane bits 2,3 (the 4 heads) in f32
        float f[8];
#pragma unroll
        for (int i = 0; i < 8; i++) f[i] = (float)A.v[i];
#pragma unroll
        for (int off = 4; off <= 8; off <<= 1)
#pragma unroll
            for (int i = 0; i < 8; i++) f[i] += __shfl_xor(f[i], off);
        if (cg < 4) {                         // 4 lanes x 8 ch = 32 outputs
            const float* bb = o ? bias2 : bias1;
            float* op = o ? out2 : out1;
            int wc = cg * 8;
            float4 r0, r1;
            r0.x = f[0] * 0.25f + bb[wc + 0];
            r0.y = f[1] * 0.25f + bb[wc + 1];
            r0.z = f[2] * 0.25f + bb[wc + 2];
            r0.w = f[3] * 0.25f + bb[wc + 3];
            r1.x = f[4] * 0.25f + bb[wc + 4];
            r1.y = f[5] * 0.25f + bb[wc + 5];
            r1.z = f[6] * 0.25f + bb[wc + 6];
            r1.w = f[7] * 0.25f + bb[wc + 7];
            *(float4*)(op + (size_t)n * 32 + wc) = r0;
            *(float4*)(op + (size_t)n * 32 + wc + 4) = r1;
        }
    }
}

// ---------------- orchestration ----------------

extern "C" void kernel_launch(void* const* d_in, const int* in_sizes, int n_in,
                              void* d_out, int out_size, void* d_ws, size_t ws_size,
                              hipStream_t stream) {
    (void)n_in; (void)out_size; (void)ws_size;
    const float* x   = (const float*)d_in[0];
    const int*   ei  = (const int*)d_in[1];
    const float* W1  = (const float*)d_in[2];
    const float* as1 = (const float*)d_in[3];
    const float* ad1 = (const float*)d_in[4];
    const float* b1  = (const float*)d_in[5];
    const float* W2  = (const float*)d_in[6];
    const float* as2 = (const float*)d_in[7];
    const float* ad2 = (const float*)d_in[8];
    const float* b2  = (const float*)d_in[9];
    const float* Wm  = (const float*)d_in[10];
    const float* a_sm = (const float*)d_in[11];
    const float* a_dm = (const float*)d_in[12];
    const float* bm  = (const float*)d_in[13];
    const float* Wl  = (const float*)d_in[14];
    const float* a_sl = (const float*)d_in[15];
    const float* a_dl = (const float*)d_in[16];
    const float* bl  = (const float*)d_in[17];
    float* outp = (float*)d_out;

    const int N  = in_sizes[0] / 256;   // 30000
    const int E  = in_sizes[1] / 2;     // 480000
    const int ET = E + N;               // with self loops
    const int gM128 = (N + 127) / 128;  // 235
    const int Mp = gM128 * 128;         // 30080 (padded rows)
    const int gM64 = (N + 63) / 64;     // 469
    const int nSB = (N + 255) / 256;    // 118 scan blocks

    auto align_up = [](size_t v) { return (v + 255) & ~(size_t)255; };
    char* w = (char*)d_ws;
    int* row_ptr = (int*)w;  w += align_up((size_t)(N + 1) * 4);
    int* cnt     = (int*)w;  w += align_up((size_t)N * 4);
    int* bsum    = (int*)w;  w += align_up((size_t)nSB * 4);
    int* csrc    = (int*)w;  w += align_up((size_t)ET * 4);
    float* al_s  = (float*)w; w += align_up((size_t)N * 8 * 4);
    float* al_d  = (float*)w; w += align_up((size_t)N * 8 * 4);
    unsigned short* xb   = (unsigned short*)w; w += align_up((size_t)Mp * 256 * 2);
    unsigned short* W1t  = (unsigned short*)w; w += align_up((size_t)256 * 256 * 2);
    unsigned short* W2t  = (unsigned short*)w; w += align_up((size_t)512 * 256 * 2);
    unsigned short* WmlT = (unsigned short*)w; w += align_up((size_t)256 * 512 * 2);
    unsigned short* bufH = (unsigned short*)w; w += align_up((size_t)Mp * 512 * 2);
    unsigned short* bufO = (unsigned short*)w; w += align_up((size_t)Mp * 512 * 2);
    // alphaT aliases xb: xb (layer-1 GEMM input) is dead after the first GEMM,
    // and every alphaT write is stream-ordered after it. 8*ET*2 = 8.2 MB <=
    // Mp*256*2 = 15.4 MB -> ws footprint unchanged.
    unsigned short* alphaT = xb;

    // ---- CSR build (count -> p1 -> p3(fused scan of totals) -> scatter) ----
    int gzE = (ET + 255) / 256;
    hipMemsetAsync(cnt, 0, (size_t)N * 4, stream);
    count_edges_kernel<<<gzE, 256, 0, stream>>>(ei, E, N, cnt);
    scan_p1_kernel<<<nSB, 256, 0, stream>>>(cnt, row_ptr, bsum, N);
    scan_p3_kernel<<<nSB, 256, 0, stream>>>(row_ptr, bsum, cnt, N, nSB);
    scatter_edges_kernel<<<gzE, 256, 0, stream>>>(ei, E, N, row_ptr, cnt, csrc);

    // ---- dtype prep (fused) ----
    int xBlocks = ((Mp * 256 / 4) + 255) / 256;
    int wBlocks = (393216 + 255) / 256;
    prep_kernel<<<xBlocks + wBlocks, 256, 0, stream>>>(
        x, xb, N, 256, Mp, W1, W2, Wm, Wl, W1t, W2t, WmlT, xBlocks);

    int gF = (N + 3) / 4;    // 7500 (alpha kernels)
    int gB = (N + 63) / 64;  // 469  (64-node agg blocks)
    int gB2 = (N + 31) / 32; // 938  (32-node mean blocks)

    // ---- Layer 1: GAT(256 -> 4x64, concat) + ReLU ----
    gemm_f16_kernel<<<dim3(2, gM64), 256, 0, stream>>>(
        xb, W1t, bufH, N, 256, 256, al_s, al_d, as1, ad1, as1, ad1, 256, 64, 4);
    alpha_kernel<1><<<gF, 256, 0, stream>>>(row_ptr, csrc, al_s, al_d, alphaT, ET, N);
    agg_stage_kernel<4, 256, 64><<<4 * gB, 256, 0, stream>>>(
        row_ptr, csrc, alphaT, ET, bufH, b1, bufO, N);

    // ---- Layer 2: GAT(256 -> 4x128, concat) + ReLU ----
    gemm_f16_kernel<<<dim3(4, gM64), 256, 0, stream>>>(
        bufO, W2t, bufH, N, 256, 512, al_s, al_d, as2, ad2, as2, ad2, 512, 128, 4);
    alpha_kernel<1><<<gF, 256, 0, stream>>>(row_ptr, csrc, al_s, al_d, alphaT, ET, N);
    agg_stage_kernel<8, 512, 128><<<8 * gB, 256, 0, stream>>>(
        row_ptr, csrc, alphaT, ET, bufH, b2, bufO, N);

    // ---- Layers 3+4 batched: GAT(512 -> 8x32, mean per 4-head group) ----
    gemm_f16_kernel<<<dim3(2, gM64), 256, 0, stream>>>(
        bufO, WmlT, bufH, N, 512, 256, al_s, al_d, a_sm, a_dm, a_sl, a_dl, 128, 32, 8);
    alpha_kernel<2><<<gF, 256, 0, stream>>>(row_ptr, csrc, al_s, al_d, alphaT, ET, N);
    agg_mean_stage_kernel<<<2 * gB2, 256, 0, stream>>>(
        row_ptr, csrc, alphaT, ET, bufH, bm, bl, outp, outp + (size_t)N * 32, N);
}

// Round 11
// 397.618 us; speedup vs baseline: 1.0243x; 1.0243x over previous
//
#include <hip/hip_runtime.h>
#include <cstddef>

typedef __attribute__((ext_vector_type(8))) short short8;
typedef __attribute__((ext_vector_type(4))) float f32x4;
typedef __attribute__((ext_vector_type(8))) _Float16 half8;
typedef __attribute__((ext_vector_type(2))) _Float16 half2v;

union H8 { half8 v; half2v p[4]; unsigned int w[4]; };
union W1H2 { unsigned int w; half2v p; };

__device__ __forceinline__ unsigned short f2h(float f) {
    union { _Float16 h; unsigned short u; } x; x.h = (_Float16)f; return x.u;
}
__device__ __forceinline__ float h2f(unsigned short u) {
    union { unsigned short u; _Float16 h; } x; x.u = u; return (float)x.h;
}
__device__ __forceinline__ float lrelu(float v) { return v > 0.f ? v : 0.2f * v; }

// async global->LDS, 16 B per lane; LDS dest is wave-uniform base + lane*16.
__device__ __forceinline__ void gl_lds16(const void* g, void* l) {
    __builtin_amdgcn_global_load_lds(
        (const __attribute__((address_space(1))) void*)g,
        (__attribute__((address_space(3))) void*)l, 16, 0, 0);
}

// ---------------- CSR build ----------------

__global__ void count_edges_kernel(const int* __restrict__ ei, int E, int N,
                                   int* __restrict__ cnt) {
    int e = blockIdx.x * blockDim.x + threadIdx.x;
    if (e >= E + N) return;
    int d = (e < E) ? ei[E + e] : (e - E);  // self loops appended
    atomicAdd(&cnt[d], 1);
}

__global__ void scan_p1_kernel(const int* __restrict__ cnt, int* __restrict__ rp,
                               int* __restrict__ bsum, int n) {
    __shared__ int sh[256];
    int t = threadIdx.x, i = blockIdx.x * 256 + t;
    sh[t] = (i < n) ? cnt[i] : 0;
    __syncthreads();
    for (int off = 1; off < 256; off <<= 1) {
        int u = (t >= off) ? sh[t - off] : 0;
        __syncthreads();
        sh[t] += u;
        __syncthreads();
    }
    if (i < n) rp[i + 1] = sh[t];              // block-local inclusive
    if (t == 255) bsum[blockIdx.x] = sh[255];  // block total
}

__global__ void scan_p3_kernel(int* __restrict__ rp, const int* __restrict__ bsum,
                               int* __restrict__ cnt, int n, int nb) {
    __shared__ int sh[256];
    int t = threadIdx.x;
    sh[t] = (t < nb) ? bsum[t] : 0;            // redundant per-block scan of totals
    __syncthreads();
    for (int off = 1; off < 256; off <<= 1) {
        int u = (t >= off) ? sh[t - off] : 0;
        __syncthreads();
        sh[t] += u;
        __syncthreads();
    }
    int off = (blockIdx.x == 0) ? 0 : sh[blockIdx.x - 1];
    int i = blockIdx.x * 256 + t;
    if (i < n) {
        rp[i + 1] += off;
        cnt[i] = 0;                            // scatter cursor re-zero
    }
    if (i == 0) rp[0] = 0;
}

__global__ void scatter_edges_kernel(const int* __restrict__ ei, int E, int N,
                                     const int* __restrict__ rp, int* __restrict__ cur,
                                     int* __restrict__ csrc) {
    int e = blockIdx.x * blockDim.x + threadIdx.x;
    if (e >= E + N) return;
    int s, d;
    if (e < E) { s = ei[e]; d = ei[E + e]; } else { s = e - E; d = s; }
    int pos = rp[d] + atomicAdd(&cur[d], 1);
    csrc[pos] = s;
}

// ---------------- dtype prep (fused: x->f16 pad + all weight transposes) ----

__global__ void prep_kernel(
    const float* __restrict__ x, unsigned short* __restrict__ xb,
    int rows, int cols, int padRows,
    const float* __restrict__ W1, const float* __restrict__ W2,
    const float* __restrict__ Wm, const float* __restrict__ Wl,
    unsigned short* __restrict__ W1t, unsigned short* __restrict__ W2t,
    unsigned short* __restrict__ WmlT, int xBlocks) {
    if ((int)blockIdx.x < xBlocks) {
        int i = blockIdx.x * blockDim.x + threadIdx.x;
        int total = (padRows * cols) >> 2;
        if (i >= total) return;
        int r = (i * 4) / cols;
        ushort4 o;
        if (r < rows) {
            float4 v = *(const float4*)(x + (size_t)i * 4);
            o = make_ushort4(f2h(v.x), f2h(v.y), f2h(v.z), f2h(v.w));
        } else {
            o = make_ushort4(0, 0, 0, 0);
        }
        *(ushort4*)(xb + (size_t)i * 4) = o;
        return;
    }
    int i = (blockIdx.x - xBlocks) * blockDim.x + threadIdx.x;
    if (i < 65536) {
        int k = i >> 8, n = i & 255;
        W1t[(size_t)n * 256 + k] = f2h(W1[i]);
    } else if (i < 65536 + 131072) {
        int j = i - 65536;
        int k = j >> 9, n = j & 511;
        W2t[(size_t)n * 256 + k] = f2h(W2[j]);
    } else if (i < 65536 + 131072 + 65536) {
        int j = i - 196608;
        int k = j >> 7, n = j & 127;
        WmlT[(size_t)n * 512 + k] = f2h(Wm[j]);
    } else if (i < 65536 + 131072 + 131072) {
        int j = i - 262144;
        int k = j >> 7, n = j & 127;
        WmlT[(size_t)(128 + n) * 512 + k] = f2h(Wl[j]);
    }
}

// ---------------- f16 MFMA GEMM (BK=64, gl_lds + XOR-swizzled LDS) ----------
// BK=64 halves the barrier count vs BK=32 (K=256: 4 steps; K=512: 8).
// 128-B LDS rows would be a full bank collapse on ds_read_b128 (G4), so the
// tile is stored XOR-swizzled: element j of row r lives at j ^ ((r&7)*8).
// gl_lds writes LDS linearly -> the swizzle is applied by pre-swizzling the
// per-lane GLOBAL source offset; fragment reads XOR with (lm&7)*8 (row
// strides are all multiples of 8, so the XOR is per-lane constant).

__global__ __launch_bounds__(256) void gemm_f16_kernel(
    const unsigned short* __restrict__ A, const unsigned short* __restrict__ Bt,
    unsigned short* __restrict__ C, int M, int K, int Nc,
    float* __restrict__ al_s, float* __restrict__ al_d,
    const float* __restrict__ aslo, const float* __restrict__ adlo,
    const float* __restrict__ ashi, const float* __restrict__ adhi,
    int csplit, int Chead, int H) {
    __shared__ short As[64 * 64];    // 8 KB, swizzled [64][64]
    __shared__ short Bs[128 * 64];   // 16 KB, swizzled [128][64]
    __shared__ float salS[64][4];
    __shared__ float salD[64][4];
    int tid = threadIdx.x;
    int bm = blockIdx.y * 64;
    int bn = blockIdx.x * 128;
    int wave = tid >> 6, lane = tid & 63;
    int wm = (wave >> 1) * 32, wn = (wave & 1) * 64;
    int lm = lane & 15, lq = lane >> 4;

    f32x4 acc[2][4] = {};

    // staging geometry: thread -> (row-in-stripe, 16B slot); stripes of 32 rows
    int wr = tid >> 3;                    // 0..31
    int wkb = (tid & 7) * 8;              // element slot base (8 elems)
    int swz = wkb ^ ((wr & 7) * 8);       // swizzled source offset (stripe-invariant)
    const unsigned short* Ar0 = A + (size_t)(bm + wr) * K + swz;
    const unsigned short* Ar1 = A + (size_t)(bm + 32 + wr) * K + swz;
    const unsigned short* Br0 = Bt + (size_t)(bn + wr) * K + swz;
    const unsigned short* Br1 = Bt + (size_t)(bn + 32 + wr) * K + swz;
    const unsigned short* Br2 = Bt + (size_t)(bn + 64 + wr) * K + swz;
    const unsigned short* Br3 = Bt + (size_t)(bn + 96 + wr) * K + swz;
    const int rswz = (lm & 7) * 8;        // fragment-read XOR (per-lane const)

    for (int kk = 0; kk < K; kk += 64) {
        __syncthreads();                  // prev iter's LDS frag reads done
        gl_lds16(Ar0 + kk, &As[tid * 8]);
        gl_lds16(Ar1 + kk, &As[2048 + tid * 8]);
        gl_lds16(Br0 + kk, &Bs[tid * 8]);
        gl_lds16(Br1 + kk, &Bs[2048 + tid * 8]);
        gl_lds16(Br2 + kk, &Bs[4096 + tid * 8]);
        gl_lds16(Br3 + kk, &Bs[6144 + tid * 8]);
        __syncthreads();                  // vmcnt drain + tile resident
#pragma unroll
        for (int ks = 0; ks < 2; ks++) {  // two K=32 sub-slices
            int kb = (ks * 32 + lq * 8) ^ rswz;
            half8 af[2], bf[4];
#pragma unroll
            for (int t = 0; t < 2; t++)
                af[t] = *(const half8*)&As[(wm + t * 16 + lm) * 64 + kb];
#pragma unroll
            for (int t = 0; t < 4; t++)
                bf[t] = *(const half8*)&Bs[(wn + t * 16 + lm) * 64 + kb];
#pragma unroll
            for (int tm = 0; tm < 2; tm++)
#pragma unroll
                for (int tn = 0; tn < 4; tn++)
                    acc[tm][tn] = __builtin_amdgcn_mfma_f32_16x16x32_f16(
                        af[tm], bf[tn], acc[tm][tn], 0, 0, 0);
        }
    }

    // C store (f16)
#pragma unroll
    for (int tm = 0; tm < 2; tm++) {
#pragma unroll
        for (int r = 0; r < 4; r++) {
            int row = bm + wm + tm * 16 + lq * 4 + r;
            if (row < M) {
#pragma unroll
                for (int tn = 0; tn < 4; tn++) {
                    int col = bn + wn + tn * 16 + lm;
                    C[(size_t)row * Nc + col] = f2h(acc[tm][tn][r]);
                }
            }
        }
    }

    // attention-logit partial dots
    float asv[4], adv[4];
#pragma unroll
    for (int tn = 0; tn < 4; tn++) {
        int col = bn + wn + tn * 16 + lm;
        bool hi = col >= csplit;
        int cc = hi ? col - csplit : col;
        asv[tn] = hi ? ashi[cc] : aslo[cc];
        adv[tn] = hi ? adhi[cc] : adlo[cc];
    }
    int gb = wn >> 5;  // 0 or 2
#pragma unroll
    for (int tm = 0; tm < 2; tm++) {
#pragma unroll
        for (int r = 0; r < 4; r++) {
#pragma unroll
            for (int p = 0; p < 2; p++) {
                float s1 = acc[tm][2 * p][r] * asv[2 * p]
                         + acc[tm][2 * p + 1][r] * asv[2 * p + 1];
                float s2 = acc[tm][2 * p][r] * adv[2 * p]
                         + acc[tm][2 * p + 1][r] * adv[2 * p + 1];
#pragma unroll
                for (int off = 8; off >= 1; off >>= 1) {
                    s1 += __shfl_xor(s1, off);
                    s2 += __shfl_xor(s2, off);
                }
                if (lm == 0) {
                    int rl = wm + tm * 16 + lq * 4 + r;
                    salS[rl][gb + p] = s1;
                    salD[rl][gb + p] = s2;
                }
            }
        }
    }
    __syncthreads();
    if (tid < 64) {
        int row = bm + tid;
        if (row < M) {
            int hb = bn / Chead;       // first head in this col-block
            int HB = 128 / Chead;      // heads per col-block (1, 2, or 4)
            int GH = Chead >> 5;       // 32-col groups per head
            for (int i = 0; i < HB; i++) {
                float ss = 0.f, sd = 0.f;
                for (int j = 0; j < GH; j++) {
                    ss += salS[tid][i * GH + j];
                    sd += salD[tid][i * GH + j];
                }
                al_s[(size_t)row * H + hb + i] = ss;
                al_d[(size_t)row * H + hb + i] = sd;
            }
        }
    }
}

// ---------------- per-node softmax -> alphaT[H][Ep] (f16) ----------------

template <int H4>
__global__ __launch_bounds__(256) void alpha_kernel(
    const int* __restrict__ rp, const int* __restrict__ csrc,
    const float* __restrict__ al_s, const float* __restrict__ al_d,
    unsigned short* __restrict__ alphaT, int Ep, int N) {
    const int H = 4 * H4;
    int wv = threadIdx.x >> 6;
    int lane = threadIdx.x & 63;
    int n = blockIdx.x * 4 + wv;
    if (n >= N) return;
    int beg = rp[n], end = rp[n + 1];
    int deg = end - beg;

    float ad[H];
#pragma unroll
    for (int g = 0; g < H4; g++)
        *(float4*)&ad[g * 4] = *(const float4*)(al_d + (size_t)n * H + g * 4);

    if (deg <= 64) {
        bool act = lane < deg;
        int s = act ? csrc[beg + lane] : 0;
        float v[H], m[H], ex[H], sum[H];
#pragma unroll
        for (int g = 0; g < H4; g++) {
            float4 as = *(const float4*)(al_s + (size_t)s * H + g * 4);
            v[g * 4 + 0] = lrelu(as.x + ad[g * 4 + 0]);
            v[g * 4 + 1] = lrelu(as.y + ad[g * 4 + 1]);
            v[g * 4 + 2] = lrelu(as.z + ad[g * 4 + 2]);
            v[g * 4 + 3] = lrelu(as.w + ad[g * 4 + 3]);
        }
#pragma unroll
        for (int j = 0; j < H; j++) m[j] = act ? v[j] : -3.402823466e38f;
#pragma unroll
        for (int off = 32; off >= 1; off >>= 1)
#pragma unroll
            for (int j = 0; j < H; j++) m[j] = fmaxf(m[j], __shfl_xor(m[j], off));
#pragma unroll
        for (int j = 0; j < H; j++) {
            ex[j] = act ? __expf(v[j] - m[j]) : 0.f;
            sum[j] = ex[j];
        }
#pragma unroll
        for (int off = 32; off >= 1; off >>= 1)
#pragma unroll
            for (int j = 0; j < H; j++) sum[j] += __shfl_xor(sum[j], off);
        if (act) {
#pragma unroll
            for (int j = 0; j < H; j++)
                alphaT[(size_t)j * Ep + beg + lane] = f2h(ex[j] / (sum[j] + 1e-16f));
        }
    } else {
        // general path (deg > 64): strided stats with recompute
        float m[H], sum[H];
#pragma unroll
        for (int j = 0; j < H; j++) m[j] = -3.402823466e38f;
        for (int e = beg + lane; e < end; e += 64) {
            int s = csrc[e];
#pragma unroll
            for (int g = 0; g < H4; g++) {
                float4 as = *(const float4*)(al_s + (size_t)s * H + g * 4);
                m[g * 4 + 0] = fmaxf(m[g * 4 + 0], lrelu(as.x + ad[g * 4 + 0]));
                m[g * 4 + 1] = fmaxf(m[g * 4 + 1], lrelu(as.y + ad[g * 4 + 1]));
                m[g * 4 + 2] = fmaxf(m[g * 4 + 2], lrelu(as.z + ad[g * 4 + 2]));
                m[g * 4 + 3] = fmaxf(m[g * 4 + 3], lrelu(as.w + ad[g * 4 + 3]));
            }
        }
#pragma unroll
        for (int off = 32; off >= 1; off >>= 1)
#pragma unroll
            for (int j = 0; j < H; j++) m[j] = fmaxf(m[j], __shfl_xor(m[j], off));
#pragma unroll
        for (int j = 0; j < H; j++) sum[j] = 0.f;
        for (int e = beg + lane; e < end; e += 64) {
            int s = csrc[e];
#pragma unroll
            for (int g = 0; g < H4; g++) {
                float4 as = *(const float4*)(al_s + (size_t)s * H + g * 4);
                sum[g * 4 + 0] += __expf(lrelu(as.x + ad[g * 4 + 0]) - m[g * 4 + 0]);
                sum[g * 4 + 1] += __expf(lrelu(as.y + ad[g * 4 + 1]) - m[g * 4 + 1]);
                sum[g * 4 + 2] += __expf(lrelu(as.z + ad[g * 4 + 2]) - m[g * 4 + 2]);
                sum[g * 4 + 3] += __expf(lrelu(as.w + ad[g * 4 + 3]) - m[g * 4 + 3]);
            }
        }
#pragma unroll
        for (int off = 32; off >= 1; off >>= 1)
#pragma unroll
            for (int j = 0; j < H; j++) sum[j] += __shfl_xor(sum[j], off);
        float r[H];
#pragma unroll
        for (int j = 0; j < H; j++) r[j] = 1.0f / (sum[j] + 1e-16f);
        for (int e = beg + lane; e < end; e += 64) {
            int s = csrc[e];
#pragma unroll
            for (int g = 0; g < H4; g++) {
                float4 as = *(const float4*)(al_s + (size_t)s * H + g * 4);
                alphaT[(size_t)(g * 4 + 0) * Ep + e] =
                    f2h(__expf(lrelu(as.x + ad[g * 4 + 0]) - m[g * 4 + 0]) * r[g * 4 + 0]);
                alphaT[(size_t)(g * 4 + 1) * Ep + e] =
                    f2h(__expf(lrelu(as.y + ad[g * 4 + 1]) - m[g * 4 + 1]) * r[g * 4 + 1]);
                alphaT[(size_t)(g * 4 + 2) * Ep + e] =
                    f2h(__expf(lrelu(as.z + ad[g * 4 + 2]) - m[g * 4 + 2]) * r[g * 4 + 2]);
                alphaT[(size_t)(g * 4 + 3) * Ep + e] =
                    f2h(__expf(lrelu(as.w + ad[g * 4 + 3]) - m[g * 4 + 3]) * r[g * 4 + 3]);
            }
        }
    }
}

// ---- staged channel-sliced aggregation (layers 1 & 2) ----
// At its practical request-rate wall (~45 us @ L2): rounds 5-10 tried five
// structurally different forms (fixed/dynamic work, 1/2/4-deep, 3 lane
// layouts) -> all 45+-1.5 us. This is the round-9 form (best measured).

template <int NS, int HC, int C>
__global__ __launch_bounds__(256) void agg_stage_kernel(
    const int* __restrict__ rp, const int* __restrict__ csrc,
    const unsigned short* __restrict__ alphaT, int Ep,
    const unsigned short* __restrict__ h, const float* __restrict__ bias,
    unsigned short* __restrict__ out, int N) {
    constexpr int NG = 32;
    constexpr int MAXE = 1024;
    __shared__ int lds_rp[NG + 1];
    __shared__ uint2 lds_ea[MAXE];            // {byte offset, packed alpha}
    int tid = threadIdx.x;
    int bs = blockIdx.x % NS;                 // channel slice (XCD-pinned)
    int g0 = (blockIdx.x / NS) * NG;          // first node of this block
    const int hd = (bs * 64) / C;             // head owning this slice
    if (tid <= NG) {
        int nn = g0 + tid;
        lds_rp[tid] = rp[nn <= N ? nn : N];
    }
    __syncthreads();
    int e0 = lds_rp[0], span = lds_rp[NG] - e0;
    const unsigned short* at = alphaT + (size_t)hd * Ep + e0;
    bool fits = span <= MAXE;
    if (fits) {
        for (int i = tid; i < span; i += 256) {   // coalesced staging
            unsigned int off = (unsigned int)csrc[e0 + i] * (unsigned int)(HC * 2);
            unsigned int a = at[i];
            lds_ea[i] = make_uint2(off, a | (a << 16));
        }
    }
    __syncthreads();

    int grp = tid >> 3;                       // group = node (0..31)
    int lg = tid & 7;                         // 8 ch-lanes per group
    int n = g0 + grp;
    if (n >= N) return;
    int ch = bs * 64 + lg * 8;
    const unsigned int lo = (unsigned int)ch * 2;   // lane-constant byte base
    const char* hb = (const char*)h;
    H8 A; A.v = half8{};

    if (fits) {
        int t = lds_rp[grp] - e0, end = lds_rp[grp + 1] - e0;
        for (; t + 3 < end; t += 4) {         // 4 loads in flight per wave
            uint2 ea0 = lds_ea[t],     ea1 = lds_ea[t + 1];
            uint2 ea2 = lds_ea[t + 2], ea3 = lds_ea[t + 3];
            H8 h0, h1, h2, h3;
            h0.v = *(const half8*)(hb + (ea0.x + lo));
            h1.v = *(const half8*)(hb + (ea1.x + lo));
            h2.v = *(const half8*)(hb + (ea2.x + lo));
            h3.v = *(const half8*)(hb + (ea3.x + lo));
            W1H2 a0, a1, a2, a3;
            a0.w = ea0.y; a1.w = ea1.y; a2.w = ea2.y; a3.w = ea3.y;
#pragma unroll
            for (int i = 0; i < 4; i++) A.p[i] += h0.p[i] * a0.p;
#pragma unroll
            for (int i = 0; i < 4; i++) A.p[i] += h1.p[i] * a1.p;
#pragma unroll
            for (int i = 0; i < 4; i++) A.p[i] += h2.p[i] * a2.p;
#pragma unroll
            for (int i = 0; i < 4; i++) A.p[i] += h3.p[i] * a3.p;
        }
        for (; t < end; t++) {
            uint2 ea0 = lds_ea[t];
            W1H2 a0; a0.w = ea0.y;
            H8 h0; h0.v = *(const half8*)(hb + (ea0.x + lo));
#pragma unroll
            for (int i = 0; i < 4; i++) A.p[i] += h0.p[i] * a0.p;
        }
    } else {                                  // pathological span: direct
        const unsigned short* atg = alphaT + (size_t)hd * Ep;
        for (int t = lds_rp[grp]; t < lds_rp[grp + 1]; t++) {
            unsigned int off = (unsigned int)csrc[t] * (unsigned int)(HC * 2);
            unsigned int a = atg[t];
            W1H2 a0; a0.w = a | (a << 16);
            H8 h0; h0.v = *(const half8*)(hb + (off + lo));
#pragma unroll
            for (int i = 0; i < 4; i++) A.p[i] += h0.p[i] * a0.p;
        }
    }

    short8 o;
#pragma unroll
    for (int i = 0; i < 8; i++)
        o[i] = (short)f2h(fmaxf((float)A.v[i] + bias[ch + i], 0.f));
    *(short8*)(out + (size_t)n * HC + ch) = o;
}

// Layers 3+4 staged: HC=256 = 8 heads x 32 ch; slice o in {0,1} covers one
// output (4 heads, 128 ch). One 16-LANE GROUP PER NODE (16 nodes/block).

__global__ __launch_bounds__(256) void agg_mean_stage_kernel(
    const int* __restrict__ rp, const int* __restrict__ csrc,
    const unsigned short* __restrict__ alphaT, int Ep,
    const unsigned short* __restrict__ h,
    const float* __restrict__ bias1, const float* __restrict__ bias2,
    float* __restrict__ out1, float* __restrict__ out2, int N) {
    constexpr int NG = 16;
    constexpr int MAXE = 1024;
    __shared__ int lds_rp[NG + 1];
    __shared__ unsigned int lds_off[MAXE];
    __shared__ unsigned int lds_aw[4][MAXE];
    int tid = threadIdx.x;
    int o = blockIdx.x & 1;                   // output slice (XCD-spread)
    int g0 = (blockIdx.x >> 1) * NG;
    if (tid <= NG) {
        int nn = g0 + tid;
        lds_rp[tid] = rp[nn <= N ? nn : N];
    }
    __syncthreads();
    int e0 = lds_rp[0], span = lds_rp[NG] - e0;
    bool fits = span <= MAXE;
    if (fits) {
        for (int i = tid; i < span; i += 256)
            lds_off[i] = (unsigned int)csrc[e0 + i] * 512u;  // 256 ch * 2 B
#pragma unroll
        for (int hh = 0; hh < 4; hh++) {
            const unsigned short* at = alphaT + (size_t)(o * 4 + hh) * Ep + e0;
            for (int i = tid; i < span; i += 256) {
                unsigned int a = at[i];
                lds_aw[hh][i] = a | (a << 16);
            }
        }
    }
    __syncthreads();

    int grp = tid >> 4;                       // group = node (0..15)
    int cg = tid & 15;                        // 16 ch-lanes per group
    int hh = cg >> 2;                         // head within slice
    int n = g0 + grp;
    if (n >= N) return;
    int ch = o * 128 + cg * 8;
    const unsigned int lo = (unsigned int)ch * 2;
    const char* hb = (const char*)h;
    H8 A; A.v = half8{};

    if (fits) {
        int t = lds_rp[grp] - e0, end = lds_rp[grp + 1] - e0;
        for (; t + 3 < end; t += 4) {         // 4 loads in flight per wave
            unsigned int o0 = lds_off[t],     o1 = lds_off[t + 1];
            unsigned int o2 = lds_off[t + 2], o3 = lds_off[t + 3];
            H8 h0, h1, h2, h3;
            h0.v = *(const half8*)(hb + (o0 + lo));
            h1.v = *(const half8*)(hb + (o1 + lo));
            h2.v = *(const half8*)(hb + (o2 + lo));
            h3.v = *(const half8*)(hb + (o3 + lo));
            W1H2 a0, a1, a2, a3;
            a0.w = lds_aw[hh][t];     a1.w = lds_aw[hh][t + 1];
            a2.w = lds_aw[hh][t + 2]; a3.w = lds_aw[hh][t + 3];
#pragma unroll
            for (int i = 0; i < 4; i++) A.p[i] += h0.p[i] * a0.p;
#pragma unroll
            for (int i = 0; i < 4; i++) A.p[i] += h1.p[i] * a1.p;
#pragma unroll
            for (int i = 0; i < 4; i++) A.p[i] += h2.p[i] * a2.p;
#pragma unroll
            for (int i = 0; i < 4; i++) A.p[i] += h3.p[i] * a3.p;
        }
        for (; t < end; t++) {
            W1H2 a0; a0.w = lds_aw[hh][t];
            H8 h0; h0.v = *(const half8*)(hb + (lds_off[t] + lo));
#pragma unroll
            for (int i = 0; i < 4; i++) A.p[i] += h0.p[i] * a0.p;
        }
    } else {
        const unsigned short* atg = alphaT + (size_t)(o * 4 + hh) * Ep;
        for (int t = lds_rp[grp]; t < lds_rp[grp + 1]; t++) {
            unsigned int off = (unsigned int)csrc[t] * 512u;
            unsigned int a = atg[t];
            W1H2 a0; a0.w = a | (a << 16);
            H8 h0; h0.v = *(const half8*)(hb + (off + lo));
#pragma unroll
            for (int i = 0; i < 4; i++) A.p[i] += h0.p[i] * a0.p;
        }
    }

    // head-mean: sum over lane bits 2,3 (the 4 heads) in f32
    float f[8];
#pragma unroll
    for (int i = 0; i < 8; i++) f[i] = (float)A.v[i];
#pragma unroll
    for (int off = 4; off <= 8; off <<= 1)
#pragma unroll
        for (int i = 0; i < 8; i++) f[i] += __shfl_xor(f[i], off);
    if (cg < 4) {                             // 4 lanes x 8 ch = 32 outputs
        const float* bb = o ? bias2 : bias1;
        float* op = o ? out2 : out1;
        int wc = cg * 8;
        float4 r0, r1;
        r0.x = f[0] * 0.25f + bb[wc + 0];
        r0.y = f[1] * 0.25f + bb[wc + 1];
        r0.z = f[2] * 0.25f + bb[wc + 2];
        r0.w = f[3] * 0.25f + bb[wc + 3];
        r1.x = f[4] * 0.25f + bb[wc + 4];
        r1.y = f[5] * 0.25f + bb[wc + 5];
        r1.z = f[6] * 0.25f + bb[wc + 6];
        r1.w = f[7] * 0.25f + bb[wc + 7];
        *(float4*)(op + (size_t)n * 32 + wc) = r0;
        *(float4*)(op + (size_t)n * 32 + wc + 4) = r1;
    }
}

// ---------------- orchestration ----------------

extern "C" void kernel_launch(void* const* d_in, const int* in_sizes, int n_in,
                              void* d_out, int out_size, void* d_ws, size_t ws_size,
                              hipStream_t stream) {
    (void)n_in; (void)out_size; (void)ws_size;
    const float* x   = (const float*)d_in[0];
    const int*   ei  = (const int*)d_in[1];
    const float* W1  = (const float*)d_in[2];
    const float* as1 = (const float*)d_in[3];
    const float* ad1 = (const float*)d_in[4];
    const float* b1  = (const float*)d_in[5];
    const float* W2  = (const float*)d_in[6];
    const float* as2 = (const float*)d_in[7];
    const float* ad2 = (const float*)d_in[8];
    const float* b2  = (const float*)d_in[9];
    const float* Wm  = (const float*)d_in[10];
    const float* a_sm = (const float*)d_in[11];
    const float* a_dm = (const float*)d_in[12];
    const float* bm  = (const float*)d_in[13];
    const float* Wl  = (const float*)d_in[14];
    const float* a_sl = (const float*)d_in[15];
    const float* a_dl = (const float*)d_in[16];
    const float* bl  = (const float*)d_in[17];
    float* outp = (float*)d_out;

    const int N  = in_sizes[0] / 256;   // 30000
    const int E  = in_sizes[1] / 2;     // 480000
    const int ET = E + N;               // with self loops
    const int gM128 = (N + 127) / 128;  // 235
    const int Mp = gM128 * 128;         // 30080 (padded rows)
    const int gM64 = (N + 63) / 64;     // 469
    const int nSB = (N + 255) / 256;    // 118 scan blocks

    auto align_up = [](size_t v) { return (v + 255) & ~(size_t)255; };
    char* w = (char*)d_ws;
    int* row_ptr = (int*)w;  w += align_up((size_t)(N + 1) * 4);
    int* cnt     = (int*)w;  w += align_up((size_t)N * 4);
    int* bsum    = (int*)w;  w += align_up((size_t)nSB * 4);
    int* csrc    = (int*)w;  w += align_up((size_t)ET * 4);
    float* al_s  = (float*)w; w += align_up((size_t)N * 8 * 4);
    float* al_d  = (float*)w; w += align_up((size_t)N * 8 * 4);
    unsigned short* xb   = (unsigned short*)w; w += align_up((size_t)Mp * 256 * 2);
    unsigned short* W1t  = (unsigned short*)w; w += align_up((size_t)256 * 256 * 2);
    unsigned short* W2t  = (unsigned short*)w; w += align_up((size_t)512 * 256 * 2);
    unsigned short* WmlT = (unsigned short*)w; w += align_up((size_t)256 * 512 * 2);
    unsigned short* bufH = (unsigned short*)w; w += align_up((size_t)Mp * 512 * 2);
    unsigned short* bufO = (unsigned short*)w; w += align_up((size_t)Mp * 512 * 2);
    // alphaT aliases xb: xb (layer-1 GEMM input) is dead after the first GEMM,
    // and every alphaT write is stream-ordered after it. 8*ET*2 = 8.2 MB <=
    // Mp*256*2 = 15.4 MB -> ws footprint unchanged.
    unsigned short* alphaT = xb;

    // ---- CSR build (count -> p1 -> p3(fused scan of totals) -> scatter) ----
    int gzE = (ET + 255) / 256;
    hipMemsetAsync(cnt, 0, (size_t)N * 4, stream);
    count_edges_kernel<<<gzE, 256, 0, stream>>>(ei, E, N, cnt);
    scan_p1_kernel<<<nSB, 256, 0, stream>>>(cnt, row_ptr, bsum, N);
    scan_p3_kernel<<<nSB, 256, 0, stream>>>(row_ptr, bsum, cnt, N, nSB);
    scatter_edges_kernel<<<gzE, 256, 0, stream>>>(ei, E, N, row_ptr, cnt, csrc);

    // ---- dtype prep (fused) ----
    int xBlocks = ((Mp * 256 / 4) + 255) / 256;
    int wBlocks = (393216 + 255) / 256;
    prep_kernel<<<xBlocks + wBlocks, 256, 0, stream>>>(
        x, xb, N, 256, Mp, W1, W2, Wm, Wl, W1t, W2t, WmlT, xBlocks);

    int gF = (N + 3) / 4;    // 7500 (alpha kernels)
    int gB = (N + 31) / 32;  // 938  (32-node agg blocks)
    int gB2 = (N + 15) / 16; // 1875 (16-node mean blocks)

    // ---- Layer 1: GAT(256 -> 4x64, concat) + ReLU ----
    gemm_f16_kernel<<<dim3(2, gM64), 256, 0, stream>>>(
        xb, W1t, bufH, N, 256, 256, al_s, al_d, as1, ad1, as1, ad1, 256, 64, 4);
    alpha_kernel<1><<<gF, 256, 0, stream>>>(row_ptr, csrc, al_s, al_d, alphaT, ET, N);
    agg_stage_kernel<4, 256, 64><<<4 * gB, 256, 0, stream>>>(
        row_ptr, csrc, alphaT, ET, bufH, b1, bufO, N);

    // ---- Layer 2: GAT(256 -> 4x128, concat) + ReLU ----
    gemm_f16_kernel<<<dim3(4, gM64), 256, 0, stream>>>(
        bufO, W2t, bufH, N, 256, 512, al_s, al_d, as2, ad2, as2, ad2, 512, 128, 4);
    alpha_kernel<1><<<gF, 256, 0, stream>>>(row_ptr, csrc, al_s, al_d, alphaT, ET, N);
    agg_stage_kernel<8, 512, 128><<<8 * gB, 256, 0, stream>>>(
        row_ptr, csrc, alphaT, ET, bufH, b2, bufO, N);

    // ---- Layers 3+4 batched: GAT(512 -> 8x32, mean per 4-head group) ----
    gemm_f16_kernel<<<dim3(2, gM64), 256, 0, stream>>>(
        bufO, WmlT, bufH, N, 512, 256, al_s, al_d, a_sm, a_dm, a_sl, a_dl, 128, 32, 8);
    alpha_kernel<2><<<gF, 256, 0, stream>>>(row_ptr, csrc, al_s, al_d, alphaT, ET, N);
    agg_mean_stage_kernel<<<2 * gB2, 256, 0, stream>>>(
        row_ptr, csrc, alphaT, ET, bufH, bm, bl, outp, outp + (size_t)N * 32, N);
}

// Round 12
// 367.419 us; speedup vs baseline: 1.1085x; 1.0822x over previous
//
#include <hip/hip_runtime.h>
#include <cstddef>

typedef __attribute__((ext_vector_type(8))) short short8;
typedef __attribute__((ext_vector_type(4))) float f32x4;
typedef __attribute__((ext_vector_type(8))) _Float16 half8;
typedef __attribute__((ext_vector_type(2))) _Float16 half2v;

union H8 { half8 v; half2v p[4]; unsigned int w[4]; };
union W1H2 { unsigned int w; half2v p; };

__device__ __forceinline__ unsigned short f2h(float f) {
    union { _Float16 h; unsigned short u; } x; x.h = (_Float16)f; return x.u;
}
__device__ __forceinline__ float h2f(unsigned short u) {
    union { unsigned short u; _Float16 h; } x; x.u = u; return (float)x.h;
}
__device__ __forceinline__ float lrelu(float v) { return v > 0.f ? v : 0.2f * v; }

// async global->LDS, 16 B per lane; LDS dest is wave-uniform base + lane*16.
__device__ __forceinline__ void gl_lds16(const void* g, void* l) {
    __builtin_amdgcn_global_load_lds(
        (const __attribute__((address_space(1))) void*)g,
        (__attribute__((address_space(3))) void*)l, 16, 0, 0);
}

// ---------------- CSR build ----------------

__global__ void scan_p1_kernel(const int* __restrict__ cnt, int* __restrict__ rp,
                               int* __restrict__ bsum, int n) {
    __shared__ int sh[256];
    int t = threadIdx.x, i = blockIdx.x * 256 + t;
    sh[t] = (i < n) ? cnt[i] : 0;
    __syncthreads();
    for (int off = 1; off < 256; off <<= 1) {
        int u = (t >= off) ? sh[t - off] : 0;
        __syncthreads();
        sh[t] += u;
        __syncthreads();
    }
    if (i < n) rp[i + 1] = sh[t];              // block-local inclusive
    if (t == 255) bsum[blockIdx.x] = sh[255];  // block total
}

__global__ void scan_p3_kernel(int* __restrict__ rp, const int* __restrict__ bsum,
                               int* __restrict__ cnt, int n, int nb) {
    __shared__ int sh[256];
    int t = threadIdx.x;
    sh[t] = (t < nb) ? bsum[t] : 0;            // redundant per-block scan of totals
    __syncthreads();
    for (int off = 1; off < 256; off <<= 1) {
        int u = (t >= off) ? sh[t - off] : 0;
        __syncthreads();
        sh[t] += u;
        __syncthreads();
    }
    int off = (blockIdx.x == 0) ? 0 : sh[blockIdx.x - 1];
    int i = blockIdx.x * 256 + t;
    if (i < n) {
        rp[i + 1] += off;
        cnt[i] = 0;                            // scatter cursor re-zero
    }
    if (i == 0) rp[0] = 0;
}

__global__ void scatter_edges_kernel(const int* __restrict__ ei, int E, int N,
                                     const int* __restrict__ rp, int* __restrict__ cur,
                                     int* __restrict__ csrc) {
    int e = blockIdx.x * blockDim.x + threadIdx.x;
    if (e >= E + N) return;
    int s, d;
    if (e < E) { s = ei[e]; d = ei[E + e]; } else { s = e - E; d = s; }
    int pos = rp[d] + atomicAdd(&cur[d], 1);
    csrc[pos] = s;
}

// ---------------- fused: edge count (CSR) + dtype prep ----------------
// Independent work items share one launch: blocks [0, czE) count edge
// destinations; [czE, czE+xBlocks) convert x->f16 padded; the rest transpose
// the four weight matrices to f16 [Nc,K].

__global__ void count_prep_kernel(
    const int* __restrict__ ei, int E, int N, int* __restrict__ cnt, int czE,
    const float* __restrict__ x, unsigned short* __restrict__ xb,
    int rows, int cols, int padRows,
    const float* __restrict__ W1, const float* __restrict__ W2,
    const float* __restrict__ Wm, const float* __restrict__ Wl,
    unsigned short* __restrict__ W1t, unsigned short* __restrict__ W2t,
    unsigned short* __restrict__ WmlT, int xBlocks) {
    int b = blockIdx.x;
    if (b < czE) {
        int e = b * blockDim.x + threadIdx.x;
        if (e >= E + N) return;
        int d = (e < E) ? ei[E + e] : (e - E);  // self loops appended
        atomicAdd(&cnt[d], 1);
        return;
    }
    b -= czE;
    if (b < xBlocks) {
        int i = b * blockDim.x + threadIdx.x;
        int total = (padRows * cols) >> 2;
        if (i >= total) return;
        int r = (i * 4) / cols;
        ushort4 o;
        if (r < rows) {
            float4 v = *(const float4*)(x + (size_t)i * 4);
            o = make_ushort4(f2h(v.x), f2h(v.y), f2h(v.z), f2h(v.w));
        } else {
            o = make_ushort4(0, 0, 0, 0);
        }
        *(ushort4*)(xb + (size_t)i * 4) = o;
        return;
    }
    int i = (b - xBlocks) * blockDim.x + threadIdx.x;
    if (i < 65536) {
        int k = i >> 8, n = i & 255;
        W1t[(size_t)n * 256 + k] = f2h(W1[i]);
    } else if (i < 65536 + 131072) {
        int j = i - 65536;
        int k = j >> 9, n = j & 511;
        W2t[(size_t)n * 256 + k] = f2h(W2[j]);
    } else if (i < 65536 + 131072 + 65536) {
        int j = i - 196608;
        int k = j >> 7, n = j & 127;
        WmlT[(size_t)n * 512 + k] = f2h(Wm[j]);
    } else if (i < 65536 + 131072 + 131072) {
        int j = i - 262144;
        int k = j >> 7, n = j & 127;
        WmlT[(size_t)(128 + n) * 512 + k] = f2h(Wl[j]);
    }
}

// ---------------- f16 MFMA GEMM (BK=64, gl_lds + XOR-swizzled LDS) ----------

__global__ __launch_bounds__(256) void gemm_f16_kernel(
    const unsigned short* __restrict__ A, const unsigned short* __restrict__ Bt,
    unsigned short* __restrict__ C, int M, int K, int Nc,
    float* __restrict__ al_s, float* __restrict__ al_d,
    const float* __restrict__ aslo, const float* __restrict__ adlo,
    const float* __restrict__ ashi, const float* __restrict__ adhi,
    int csplit, int Chead, int H) {
    __shared__ short As[64 * 64];    // 8 KB, swizzled [64][64]
    __shared__ short Bs[128 * 64];   // 16 KB, swizzled [128][64]
    __shared__ float salS[64][4];
    __shared__ float salD[64][4];
    int tid = threadIdx.x;
    int bm = blockIdx.y * 64;
    int bn = blockIdx.x * 128;
    int wave = tid >> 6, lane = tid & 63;
    int wm = (wave >> 1) * 32, wn = (wave & 1) * 64;
    int lm = lane & 15, lq = lane >> 4;

    f32x4 acc[2][4] = {};

    // staging geometry: thread -> (row-in-stripe, 16B slot); stripes of 32 rows
    int wr = tid >> 3;                    // 0..31
    int wkb = (tid & 7) * 8;              // element slot base (8 elems)
    int swz = wkb ^ ((wr & 7) * 8);       // swizzled source offset (stripe-invariant)
    const unsigned short* Ar0 = A + (size_t)(bm + wr) * K + swz;
    const unsigned short* Ar1 = A + (size_t)(bm + 32 + wr) * K + swz;
    const unsigned short* Br0 = Bt + (size_t)(bn + wr) * K + swz;
    const unsigned short* Br1 = Bt + (size_t)(bn + 32 + wr) * K + swz;
    const unsigned short* Br2 = Bt + (size_t)(bn + 64 + wr) * K + swz;
    const unsigned short* Br3 = Bt + (size_t)(bn + 96 + wr) * K + swz;
    const int rswz = (lm & 7) * 8;        // fragment-read XOR (per-lane const)

    for (int kk = 0; kk < K; kk += 64) {
        __syncthreads();                  // prev iter's LDS frag reads done
        gl_lds16(Ar0 + kk, &As[tid * 8]);
        gl_lds16(Ar1 + kk, &As[2048 + tid * 8]);
        gl_lds16(Br0 + kk, &Bs[tid * 8]);
        gl_lds16(Br1 + kk, &Bs[2048 + tid * 8]);
        gl_lds16(Br2 + kk, &Bs[4096 + tid * 8]);
        gl_lds16(Br3 + kk, &Bs[6144 + tid * 8]);
        __syncthreads();                  // vmcnt drain + tile resident
#pragma unroll
        for (int ks = 0; ks < 2; ks++) {  // two K=32 sub-slices
            int kb = (ks * 32 + lq * 8) ^ rswz;
            half8 af[2], bf[4];
#pragma unroll
            for (int t = 0; t < 2; t++)
                af[t] = *(const half8*)&As[(wm + t * 16 + lm) * 64 + kb];
#pragma unroll
            for (int t = 0; t < 4; t++)
                bf[t] = *(const half8*)&Bs[(wn + t * 16 + lm) * 64 + kb];
#pragma unroll
            for (int tm = 0; tm < 2; tm++)
#pragma unroll
                for (int tn = 0; tn < 4; tn++)
                    acc[tm][tn] = __builtin_amdgcn_mfma_f32_16x16x32_f16(
                        af[tm], bf[tn], acc[tm][tn], 0, 0, 0);
        }
    }

    // C store (f16)
#pragma unroll
    for (int tm = 0; tm < 2; tm++) {
#pragma unroll
        for (int r = 0; r < 4; r++) {
            int row = bm + wm + tm * 16 + lq * 4 + r;
            if (row < M) {
#pragma unroll
                for (int tn = 0; tn < 4; tn++) {
                    int col = bn + wn + tn * 16 + lm;
                    C[(size_t)row * Nc + col] = f2h(acc[tm][tn][r]);
                }
            }
        }
    }

    // attention-logit partial dots
    float asv[4], adv[4];
#pragma unroll
    for (int tn = 0; tn < 4; tn++) {
        int col = bn + wn + tn * 16 + lm;
        bool hi = col >= csplit;
        int cc = hi ? col - csplit : col;
        asv[tn] = hi ? ashi[cc] : aslo[cc];
        adv[tn] = hi ? adhi[cc] : adlo[cc];
    }
    int gb = wn >> 5;  // 0 or 2
#pragma unroll
    for (int tm = 0; tm < 2; tm++) {
#pragma unroll
        for (int r = 0; r < 4; r++) {
#pragma unroll
            for (int p = 0; p < 2; p++) {
                float s1 = acc[tm][2 * p][r] * asv[2 * p]
                         + acc[tm][2 * p + 1][r] * asv[2 * p + 1];
                float s2 = acc[tm][2 * p][r] * adv[2 * p]
                         + acc[tm][2 * p + 1][r] * adv[2 * p + 1];
#pragma unroll
                for (int off = 8; off >= 1; off >>= 1) {
                    s1 += __shfl_xor(s1, off);
                    s2 += __shfl_xor(s2, off);
                }
                if (lm == 0) {
                    int rl = wm + tm * 16 + lq * 4 + r;
                    salS[rl][gb + p] = s1;
                    salD[rl][gb + p] = s2;
                }
            }
        }
    }
    __syncthreads();
    if (tid < 64) {
        int row = bm + tid;
        if (row < M) {
            int hb = bn / Chead;       // first head in this col-block
            int HB = 128 / Chead;      // heads per col-block (1, 2, or 4)
            int GH = Chead >> 5;       // 32-col groups per head
            for (int i = 0; i < HB; i++) {
                float ss = 0.f, sd = 0.f;
                for (int j = 0; j < GH; j++) {
                    ss += salS[tid][i * GH + j];
                    sd += salD[tid][i * GH + j];
                }
                al_s[(size_t)row * H + hb + i] = ss;
                al_d[(size_t)row * H + hb + i] = sd;
            }
        }
    }
}

// ---------------- per-node softmax -> alphaT[H][Ep] (f16) ----------------
// TWO nodes per wave (32-lane sub-waves): mean deg ~17 left 73% of a 64-lane
// wave idle. deg<=32 covers ~4 sigma of the degree distribution; the rare
// deg>32 node falls to a strided general path (stride 32). All shuffles use
// offsets <=16 so they never cross the 32-lane sub-wave boundary, and deg is
// sub-wave-uniform so branching is safe.

template <int H4>
__global__ __launch_bounds__(256) void alpha_kernel(
    const int* __restrict__ rp, const int* __restrict__ csrc,
    const float* __restrict__ al_s, const float* __restrict__ al_d,
    unsigned short* __restrict__ alphaT, int Ep, int N) {
    const int H = 4 * H4;
    int sub = threadIdx.x >> 5;               // 8 sub-waves of 32 lanes
    int lane = threadIdx.x & 31;
    int n = blockIdx.x * 8 + sub;
    if (n >= N) return;
    int beg = rp[n], end = rp[n + 1];
    int deg = end - beg;

    float ad[H];
#pragma unroll
    for (int g = 0; g < H4; g++)
        *(float4*)&ad[g * 4] = *(const float4*)(al_d + (size_t)n * H + g * 4);

    if (deg <= 32) {
        bool act = lane < deg;
        int s = act ? csrc[beg + lane] : 0;
        float v[H], m[H], ex[H], sum[H];
#pragma unroll
        for (int g = 0; g < H4; g++) {
            float4 as = *(const float4*)(al_s + (size_t)s * H + g * 4);
            v[g * 4 + 0] = lrelu(as.x + ad[g * 4 + 0]);
            v[g * 4 + 1] = lrelu(as.y + ad[g * 4 + 1]);
            v[g * 4 + 2] = lrelu(as.z + ad[g * 4 + 2]);
            v[g * 4 + 3] = lrelu(as.w + ad[g * 4 + 3]);
        }
#pragma unroll
        for (int j = 0; j < H; j++) m[j] = act ? v[j] : -3.402823466e38f;
#pragma unroll
        for (int off = 16; off >= 1; off >>= 1)
#pragma unroll
            for (int j = 0; j < H; j++) m[j] = fmaxf(m[j], __shfl_xor(m[j], off));
#pragma unroll
        for (int j = 0; j < H; j++) {
            ex[j] = act ? __expf(v[j] - m[j]) : 0.f;
            sum[j] = ex[j];
        }
#pragma unroll
        for (int off = 16; off >= 1; off >>= 1)
#pragma unroll
            for (int j = 0; j < H; j++) sum[j] += __shfl_xor(sum[j], off);
        if (act) {
#pragma unroll
            for (int j = 0; j < H; j++)
                alphaT[(size_t)j * Ep + beg + lane] = f2h(ex[j] / (sum[j] + 1e-16f));
        }
    } else {
        // general path (deg > 32): strided stats with recompute, stride 32
        float m[H], sum[H];
#pragma unroll
        for (int j = 0; j < H; j++) m[j] = -3.402823466e38f;
        for (int e = beg + lane; e < end; e += 32) {
            int s = csrc[e];
#pragma unroll
            for (int g = 0; g < H4; g++) {
                float4 as = *(const float4*)(al_s + (size_t)s * H + g * 4);
                m[g * 4 + 0] = fmaxf(m[g * 4 + 0], lrelu(as.x + ad[g * 4 + 0]));
                m[g * 4 + 1] = fmaxf(m[g * 4 + 1], lrelu(as.y + ad[g * 4 + 1]));
                m[g * 4 + 2] = fmaxf(m[g * 4 + 2], lrelu(as.z + ad[g * 4 + 2]));
                m[g * 4 + 3] = fmaxf(m[g * 4 + 3], lrelu(as.w + ad[g * 4 + 3]));
            }
        }
#pragma unroll
        for (int off = 16; off >= 1; off >>= 1)
#pragma unroll
            for (int j = 0; j < H; j++) m[j] = fmaxf(m[j], __shfl_xor(m[j], off));
#pragma unroll
        for (int j = 0; j < H; j++) sum[j] = 0.f;
        for (int e = beg + lane; e < end; e += 32) {
            int s = csrc[e];
#pragma unroll
            for (int g = 0; g < H4; g++) {
                float4 as = *(const float4*)(al_s + (size_t)s * H + g * 4);
                sum[g * 4 + 0] += __expf(lrelu(as.x + ad[g * 4 + 0]) - m[g * 4 + 0]);
                sum[g * 4 + 1] += __expf(lrelu(as.y + ad[g * 4 + 1]) - m[g * 4 + 1]);
                sum[g * 4 + 2] += __expf(lrelu(as.z + ad[g * 4 + 2]) - m[g * 4 + 2]);
                sum[g * 4 + 3] += __expf(lrelu(as.w + ad[g * 4 + 3]) - m[g * 4 + 3]);
            }
        }
#pragma unroll
        for (int off = 16; off >= 1; off >>= 1)
#pragma unroll
            for (int j = 0; j < H; j++) sum[j] += __shfl_xor(sum[j], off);
        float r[H];
#pragma unroll
        for (int j = 0; j < H; j++) r[j] = 1.0f / (sum[j] + 1e-16f);
        for (int e = beg + lane; e < end; e += 32) {
            int s = csrc[e];
#pragma unroll
            for (int g = 0; g < H4; g++) {
                float4 as = *(const float4*)(al_s + (size_t)s * H + g * 4);
                alphaT[(size_t)(g * 4 + 0) * Ep + e] =
                    f2h(__expf(lrelu(as.x + ad[g * 4 + 0]) - m[g * 4 + 0]) * r[g * 4 + 0]);
                alphaT[(size_t)(g * 4 + 1) * Ep + e] =
                    f2h(__expf(lrelu(as.y + ad[g * 4 + 1]) - m[g * 4 + 1]) * r[g * 4 + 1]);
                alphaT[(size_t)(g * 4 + 2) * Ep + e] =
                    f2h(__expf(lrelu(as.z + ad[g * 4 + 2]) - m[g * 4 + 2]) * r[g * 4 + 2]);
                alphaT[(size_t)(g * 4 + 3) * Ep + e] =
                    f2h(__expf(lrelu(as.w + ad[g * 4 + 3]) - m[g * 4 + 3]) * r[g * 4 + 3]);
            }
        }
    }
}

// ---- staged channel-sliced aggregation (layers 1 & 2) ----
// At its practical request-rate wall (~45 us @ L2): rounds 5-10 tried five
// structurally different forms (fixed/dynamic work, 1/2/4-deep, 3 lane
// layouts) -> all 45+-1.5 us. This is the round-9 form (best measured).

template <int NS, int HC, int C>
__global__ __launch_bounds__(256) void agg_stage_kernel(
    const int* __restrict__ rp, const int* __restrict__ csrc,
    const unsigned short* __restrict__ alphaT, int Ep,
    const unsigned short* __restrict__ h, const float* __restrict__ bias,
    unsigned short* __restrict__ out, int N) {
    constexpr int NG = 32;
    constexpr int MAXE = 1024;
    __shared__ int lds_rp[NG + 1];
    __shared__ uint2 lds_ea[MAXE];            // {byte offset, packed alpha}
    int tid = threadIdx.x;
    int bs = blockIdx.x % NS;                 // channel slice (XCD-pinned)
    int g0 = (blockIdx.x / NS) * NG;          // first node of this block
    const int hd = (bs * 64) / C;             // head owning this slice
    if (tid <= NG) {
        int nn = g0 + tid;
        lds_rp[tid] = rp[nn <= N ? nn : N];
    }
    __syncthreads();
    int e0 = lds_rp[0], span = lds_rp[NG] - e0;
    const unsigned short* at = alphaT + (size_t)hd * Ep + e0;
    bool fits = span <= MAXE;
    if (fits) {
        for (int i = tid; i < span; i += 256) {   // coalesced staging
            unsigned int off = (unsigned int)csrc[e0 + i] * (unsigned int)(HC * 2);
            unsigned int a = at[i];
            lds_ea[i] = make_uint2(off, a | (a << 16));
        }
    }
    __syncthreads();

    int grp = tid >> 3;                       // group = node (0..31)
    int lg = tid & 7;                         // 8 ch-lanes per group
    int n = g0 + grp;
    if (n >= N) return;
    int ch = bs * 64 + lg * 8;
    const unsigned int lo = (unsigned int)ch * 2;   // lane-constant byte base
    const char* hb = (const char*)h;
    H8 A; A.v = half8{};

    if (fits) {
        int t = lds_rp[grp] - e0, end = lds_rp[grp + 1] - e0;
        for (; t + 3 < end; t += 4) {         // 4 loads in flight per wave
            uint2 ea0 = lds_ea[t],     ea1 = lds_ea[t + 1];
            uint2 ea2 = lds_ea[t + 2], ea3 = lds_ea[t + 3];
            H8 h0, h1, h2, h3;
            h0.v = *(const half8*)(hb + (ea0.x + lo));
            h1.v = *(const half8*)(hb + (ea1.x + lo));
            h2.v = *(const half8*)(hb + (ea2.x + lo));
            h3.v = *(const half8*)(hb + (ea3.x + lo));
            W1H2 a0, a1, a2, a3;
            a0.w = ea0.y; a1.w = ea1.y; a2.w = ea2.y; a3.w = ea3.y;
#pragma unroll
            for (int i = 0; i < 4; i++) A.p[i] += h0.p[i] * a0.p;
#pragma unroll
            for (int i = 0; i < 4; i++) A.p[i] += h1.p[i] * a1.p;
#pragma unroll
            for (int i = 0; i < 4; i++) A.p[i] += h2.p[i] * a2.p;
#pragma unroll
            for (int i = 0; i < 4; i++) A.p[i] += h3.p[i] * a3.p;
        }
        for (; t < end; t++) {
            uint2 ea0 = lds_ea[t];
            W1H2 a0; a0.w = ea0.y;
            H8 h0; h0.v = *(const half8*)(hb + (ea0.x + lo));
#pragma unroll
            for (int i = 0; i < 4; i++) A.p[i] += h0.p[i] * a0.p;
        }
    } else {                                  // pathological span: direct
        const unsigned short* atg = alphaT + (size_t)hd * Ep;
        for (int t = lds_rp[grp]; t < lds_rp[grp + 1]; t++) {
            unsigned int off = (unsigned int)csrc[t] * (unsigned int)(HC * 2);
            unsigned int a = atg[t];
            W1H2 a0; a0.w = a | (a << 16);
            H8 h0; h0.v = *(const half8*)(hb + (off + lo));
#pragma unroll
            for (int i = 0; i < 4; i++) A.p[i] += h0.p[i] * a0.p;
        }
    }

    short8 o;
#pragma unroll
    for (int i = 0; i < 8; i++)
        o[i] = (short)f2h(fmaxf((float)A.v[i] + bias[ch + i], 0.f));
    *(short8*)(out + (size_t)n * HC + ch) = o;
}

// Layers 3+4 staged: HC=256 = 8 heads x 32 ch; slice o in {0,1} covers one
// output (4 heads, 128 ch). One 16-LANE GROUP PER NODE (16 nodes/block).

__global__ __launch_bounds__(256) void agg_mean_stage_kernel(
    const int* __restrict__ rp, const int* __restrict__ csrc,
    const unsigned short* __restrict__ alphaT, int Ep,
    const unsigned short* __restrict__ h,
    const float* __restrict__ bias1, const float* __restrict__ bias2,
    float* __restrict__ out1, float* __restrict__ out2, int N) {
    constexpr int NG = 16;
    constexpr int MAXE = 1024;
    __shared__ int lds_rp[NG + 1];
    __shared__ unsigned int lds_off[MAXE];
    __shared__ unsigned int lds_aw[4][MAXE];
    int tid = threadIdx.x;
    int o = blockIdx.x & 1;                   // output slice (XCD-spread)
    int g0 = (blockIdx.x >> 1) * NG;
    if (tid <= NG) {
        int nn = g0 + tid;
        lds_rp[tid] = rp[nn <= N ? nn : N];
    }
    __syncthreads();
    int e0 = lds_rp[0], span = lds_rp[NG] - e0;
    bool fits = span <= MAXE;
    if (fits) {
        for (int i = tid; i < span; i += 256)
            lds_off[i] = (unsigned int)csrc[e0 + i] * 512u;  // 256 ch * 2 B
#pragma unroll
        for (int hh = 0; hh < 4; hh++) {
            const unsigned short* at = alphaT + (size_t)(o * 4 + hh) * Ep + e0;
            for (int i = tid; i < span; i += 256) {
                unsigned int a = at[i];
                lds_aw[hh][i] = a | (a << 16);
            }
        }
    }
    __syncthreads();

    int grp = tid >> 4;                       // group = node (0..15)
    int cg = tid & 15;                        // 16 ch-lanes per group
    int hh = cg >> 2;                         // head within slice
    int n = g0 + grp;
    if (n >= N) return;
    int ch = o * 128 + cg * 8;
    const unsigned int lo = (unsigned int)ch * 2;
    const char* hb = (const char*)h;
    H8 A; A.v = half8{};

    if (fits) {
        int t = lds_rp[grp] - e0, end = lds_rp[grp + 1] - e0;
        for (; t + 3 < end; t += 4) {         // 4 loads in flight per wave
            unsigned int o0 = lds_off[t],     o1 = lds_off[t + 1];
            unsigned int o2 = lds_off[t + 2], o3 = lds_off[t + 3];
            H8 h0, h1, h2, h3;
            h0.v = *(const half8*)(hb + (o0 + lo));
            h1.v = *(const half8*)(hb + (o1 + lo));
            h2.v = *(const half8*)(hb + (o2 + lo));
            h3.v = *(const half8*)(hb + (o3 + lo));
            W1H2 a0, a1, a2, a3;
            a0.w = lds_aw[hh][t];     a1.w = lds_aw[hh][t + 1];
            a2.w = lds_aw[hh][t + 2]; a3.w = lds_aw[hh][t + 3];
#pragma unroll
            for (int i = 0; i < 4; i++) A.p[i] += h0.p[i] * a0.p;
#pragma unroll
            for (int i = 0; i < 4; i++) A.p[i] += h1.p[i] * a1.p;
#pragma unroll
            for (int i = 0; i < 4; i++) A.p[i] += h2.p[i] * a2.p;
#pragma unroll
            for (int i = 0; i < 4; i++) A.p[i] += h3.p[i] * a3.p;
        }
        for (; t < end; t++) {
            W1H2 a0; a0.w = lds_aw[hh][t];
            H8 h0; h0.v = *(const half8*)(hb + (lds_off[t] + lo));
#pragma unroll
            for (int i = 0; i < 4; i++) A.p[i] += h0.p[i] * a0.p;
        }
    } else {
        const unsigned short* atg = alphaT + (size_t)(o * 4 + hh) * Ep;
        for (int t = lds_rp[grp]; t < lds_rp[grp + 1]; t++) {
            unsigned int off = (unsigned int)csrc[t] * 512u;
            unsigned int a = atg[t];
            W1H2 a0; a0.w = a | (a << 16);
            H8 h0; h0.v = *(const half8*)(hb + (off + lo));
#pragma unroll
            for (int i = 0; i < 4; i++) A.p[i] += h0.p[i] * a0.p;
        }
    }

    // head-mean: sum over lane bits 2,3 (the 4 heads) in f32
    float f[8];
#pragma unroll
    for (int i = 0; i < 8; i++) f[i] = (float)A.v[i];
#pragma unroll
    for (int off = 4; off <= 8; off <<= 1)
#pragma unroll
        for (int i = 0; i < 8; i++) f[i] += __shfl_xor(f[i], off);
    if (cg < 4) {                             // 4 lanes x 8 ch = 32 outputs
        const float* bb = o ? bias2 : bias1;
        float* op = o ? out2 : out1;
        int wc = cg * 8;
        float4 r0, r1;
        r0.x = f[0] * 0.25f + bb[wc + 0];
        r0.y = f[1] * 0.25f + bb[wc + 1];
        r0.z = f[2] * 0.25f + bb[wc + 2];
        r0.w = f[3] * 0.25f + bb[wc + 3];
        r1.x = f[4] * 0.25f + bb[wc + 4];
        r1.y = f[5] * 0.25f + bb[wc + 5];
        r1.z = f[6] * 0.25f + bb[wc + 6];
        r1.w = f[7] * 0.25f + bb[wc + 7];
        *(float4*)(op + (size_t)n * 32 + wc) = r0;
        *(float4*)(op + (size_t)n * 32 + wc + 4) = r1;
    }
}

// ---------------- orchestration ----------------

extern "C" void kernel_launch(void* const* d_in, const int* in_sizes, int n_in,
                              void* d_out, int out_size, void* d_ws, size_t ws_size,
                              hipStream_t stream) {
    (void)n_in; (void)out_size; (void)ws_size;
    const float* x   = (const float*)d_in[0];
    const int*   ei  = (const int*)d_in[1];
    const float* W1  = (const float*)d_in[2];
    const float* as1 = (const float*)d_in[3];
    const float* ad1 = (const float*)d_in[4];
    const float* b1  = (const float*)d_in[5];
    const float* W2  = (const float*)d_in[6];
    const float* as2 = (const float*)d_in[7];
    const float* ad2 = (const float*)d_in[8];
    const float* b2  = (const float*)d_in[9];
    const float* Wm  = (const float*)d_in[10];
    const float* a_sm = (const float*)d_in[11];
    const float* a_dm = (const float*)d_in[12];
    const float* bm  = (const float*)d_in[13];
    const float* Wl  = (const float*)d_in[14];
    const float* a_sl = (const float*)d_in[15];
    const float* a_dl = (const float*)d_in[16];
    const float* bl  = (const float*)d_in[17];
    float* outp = (float*)d_out;

    const int N  = in_sizes[0] / 256;   // 30000
    const int E  = in_sizes[1] / 2;     // 480000
    const int ET = E + N;               // with self loops
    const int gM128 = (N + 127) / 128;  // 235
    const int Mp = gM128 * 128;         // 30080 (padded rows)
    const int gM64 = (N + 63) / 64;     // 469
    const int nSB = (N + 255) / 256;    // 118 scan blocks

    auto align_up = [](size_t v) { return (v + 255) & ~(size_t)255; };
    char* w = (char*)d_ws;
    int* row_ptr = (int*)w;  w += align_up((size_t)(N + 1) * 4);
    int* cnt     = (int*)w;  w += align_up((size_t)N * 4);
    int* bsum    = (int*)w;  w += align_up((size_t)nSB * 4);
    int* csrc    = (int*)w;  w += align_up((size_t)ET * 4);
    float* al_s  = (float*)w; w += align_up((size_t)N * 8 * 4);
    float* al_d  = (float*)w; w += align_up((size_t)N * 8 * 4);
    unsigned short* xb   = (unsigned short*)w; w += align_up((size_t)Mp * 256 * 2);
    unsigned short* W1t  = (unsigned short*)w; w += align_up((size_t)256 * 256 * 2);
    unsigned short* W2t  = (unsigned short*)w; w += align_up((size_t)512 * 256 * 2);
    unsigned short* WmlT = (unsigned short*)w; w += align_up((size_t)256 * 512 * 2);
    unsigned short* bufH = (unsigned short*)w; w += align_up((size_t)Mp * 512 * 2);
    unsigned short* bufO = (unsigned short*)w; w += align_up((size_t)Mp * 512 * 2);
    // alphaT aliases xb: xb (layer-1 GEMM input) is dead after the first GEMM,
    // and every alphaT write is stream-ordered after it. 8*ET*2 = 8.2 MB <=
    // Mp*256*2 = 15.4 MB -> ws footprint unchanged.
    unsigned short* alphaT = xb;

    // ---- CSR build + prep (count fused with dtype prep) ----
    int gzE = (ET + 255) / 256;
    int xBlocks = ((Mp * 256 / 4) + 255) / 256;
    int wBlocks = (393216 + 255) / 256;
    hipMemsetAsync(cnt, 0, (size_t)N * 4, stream);
    count_prep_kernel<<<gzE + xBlocks + wBlocks, 256, 0, stream>>>(
        ei, E, N, cnt, gzE, x, xb, N, 256, Mp,
        W1, W2, Wm, Wl, W1t, W2t, WmlT, xBlocks);
    scan_p1_kernel<<<nSB, 256, 0, stream>>>(cnt, row_ptr, bsum, N);
    scan_p3_kernel<<<nSB, 256, 0, stream>>>(row_ptr, bsum, cnt, N, nSB);
    scatter_edges_kernel<<<gzE, 256, 0, stream>>>(ei, E, N, row_ptr, cnt, csrc);

    int gF = (N + 7) / 8;    // 3750 (alpha kernels, 8 nodes/block)
    int gB = (N + 31) / 32;  // 938  (32-node agg blocks)
    int gB2 = (N + 15) / 16; // 1875 (16-node mean blocks)

    // ---- Layer 1: GAT(256 -> 4x64, concat) + ReLU ----
    gemm_f16_kernel<<<dim3(2, gM64), 256, 0, stream>>>(
        xb, W1t, bufH, N, 256, 256, al_s, al_d, as1, ad1, as1, ad1, 256, 64, 4);
    alpha_kernel<1><<<gF, 256, 0, stream>>>(row_ptr, csrc, al_s, al_d, alphaT, ET, N);
    agg_stage_kernel<4, 256, 64><<<4 * gB, 256, 0, stream>>>(
        row_ptr, csrc, alphaT, ET, bufH, b1, bufO, N);

    // ---- Layer 2: GAT(256 -> 4x128, concat) + ReLU ----
    gemm_f16_kernel<<<dim3(4, gM64), 256, 0, stream>>>(
        bufO, W2t, bufH, N, 256, 512, al_s, al_d, as2, ad2, as2, ad2, 512, 128, 4);
    alpha_kernel<1><<<gF, 256, 0, stream>>>(row_ptr, csrc, al_s, al_d, alphaT, ET, N);
    agg_stage_kernel<8, 512, 128><<<8 * gB, 256, 0, stream>>>(
        row_ptr, csrc, alphaT, ET, bufH, b2, bufO, N);

    // ---- Layers 3+4 batched: GAT(512 -> 8x32, mean per 4-head group) ----
    gemm_f16_kernel<<<dim3(2, gM64), 256, 0, stream>>>(
        bufO, WmlT, bufH, N, 512, 256, al_s, al_d, a_sm, a_dm, a_sl, a_dl, 128, 32, 8);
    alpha_kernel<2><<<gF, 256, 0, stream>>>(row_ptr, csrc, al_s, al_d, alphaT, ET, N);
    agg_mean_stage_kernel<<<2 * gB2, 256, 0, stream>>>(
        row_ptr, csrc, alphaT, ET, bufH, bm, bl, outp, outp + (size_t)N * 32, N);
}